// Round 8
// baseline (563.298 us; speedup 1.0000x reference)
//
#include <hip/hip_runtime.h>
#include <math.h>

// ---------------- problem constants ----------------
#define B_ROWS 65536
#define D_IN   512
#define HDIM   512
#define FAN    1024          // D_IN + HDIM
#define NCOL   2048          // 4 gates * HDIM
#define EPS    1e-5f

// GEMM tile (256^2 8-phase template, one output tile per block)
#define BM 256
#define BN 256
#define BK 64
#define KTILES (FAN / BK)    // 16
#define NITER  (KTILES / 2)  // 8 iterations, 2 K-tiles each

typedef unsigned short u16;
using bfrag = __attribute__((ext_vector_type(8))) short;          // 8 bf16 (4 VGPRs)
using facc  = __attribute__((ext_vector_type(4))) float;          // 4 fp32 acc
using us4   = __attribute__((ext_vector_type(4))) unsigned short;
using us8   = __attribute__((ext_vector_type(8))) unsigned short;

// ---------------- helpers ----------------
static __device__ __forceinline__ u16 f2b(float f) {              // fp32 -> bf16 RNE
    unsigned u = __builtin_bit_cast(unsigned, f);
    u += 0x7fffu + ((u >> 16) & 1u);
    return (u16)(u >> 16);
}
static __device__ __forceinline__ float b2f(u16 h) {
    unsigned u = ((unsigned)h) << 16;
    return __builtin_bit_cast(float, u);
}
static __device__ __forceinline__ void gload16(const u16* g, u16* l) {
    __builtin_amdgcn_global_load_lds(
        (const __attribute__((address_space(1))) void*)g,
        (__attribute__((address_space(3))) void*)l, 16, 0, 0);
}
static __device__ __forceinline__ void wave_meanrstd(float s, float ss, float& mean, float& rstd)
{
#pragma unroll
    for (int o = 1; o < 64; o <<= 1) { s += __shfl_xor(s, o); ss += __shfl_xor(ss, o); }
    mean = s * (1.f / 512.f);
    float var = (ss - 512.f * mean * mean) * (1.f / 511.f);
    rstd = 1.f / (sqrtf(fmaxf(var, 0.f)) + EPS);
}
static __device__ __forceinline__ float fast_sigmoid(float z) {
    return __fdividef(1.f, 1.f + __expf(-z));
}
static __device__ __forceinline__ float fast_tanh(float z) {
    return __fdividef(2.f, 1.f + __expf(-2.f * z)) - 1.f;
}

// ---------------- kernel 0a: pack combined = concat(x, prev_h) as bf16 ----------------
__global__ void pack_combined(const float* __restrict__ x, const float* __restrict__ ph,
                              u16* __restrict__ comb)
{
    long i = (long)blockIdx.x * 256 + threadIdx.x;
    if (i >= (long)B_ROWS * D_IN / 4) return;
    long e = i * 4;
    long b = e >> 9;
    int  d = (int)(e & 511);
    float4 xv = *(const float4*)(x + e);
    float4 hv = *(const float4*)(ph + e);
    us4 xb = { f2b(xv.x), f2b(xv.y), f2b(xv.z), f2b(xv.w) };
    us4 hb = { f2b(hv.x), f2b(hv.y), f2b(hv.z), f2b(hv.w) };
    *(us4*)(comb + b * FAN + d)        = xb;
    *(us4*)(comb + b * FAN + D_IN + d) = hb;
}

// ---------------- kernel 0b: pack W = [Wf;Wi;Wo;Wj] as bf16 [2048][1024] ----------------
__global__ void pack_w(const float* __restrict__ Wf, const float* __restrict__ Wi,
                       const float* __restrict__ Wo, const float* __restrict__ Wj,
                       u16* __restrict__ Wall)
{
    long i = (long)blockIdx.x * 256 + threadIdx.x;
    if (i >= (long)NCOL * FAN / 4) return;
    long e = i * 4;
    int  g = (int)(e >> 19);
    long rem = e & 524287L;
    const float* src = (g == 0) ? Wf : (g == 1) ? Wi : (g == 2) ? Wo : Wj;
    float4 v = *(const float4*)(src + rem);
    us4 p = { f2b(v.x), f2b(v.y), f2b(v.z), f2b(v.w) };
    *(us4*)(Wall + e) = p;
}

// ---------------- kernel 1: 256^2 8-phase GEMM, one tile/block ------------------------
// n-fastest wg order inside the XCD swizzle -> the 8 N-blocks of one M-panel are
// co-resident per XCD and share the A-panel in L2 (round-5 config: FETCH 197 MB).
// OPERAND-SWAPPED mfma: D col=lane&15 -> M-row, reg -> 4 consecutive N-cols, so the
// epilogue is 32 packed 8B us4 stores per thread (full 32B sectors, no L2 RMW,
// no LDS restage, no restage bank conflicts).
__global__ __launch_bounds__(512)
void gemm_gates(const u16* __restrict__ A, const u16* __restrict__ W, u16* __restrict__ Cg)
{
    __shared__ u16 lds[2][4][8192];

    const int tid  = threadIdx.x;
    const int lane = tid & 63;
    const int wid  = tid >> 6;
    const int wm   = wid >> 2;         // 0..1
    const int wn   = wid & 3;          // 0..3

    // XCD-aware bijective swizzle (nwg = mtiles*8, always a multiple of 8)
    const int nwg = gridDim.x;
    const int wg  = (blockIdx.x & 7) * (nwg >> 3) + (blockIdx.x >> 3);
    const long bm = wg >> 3;           // n-fastest within the XCD's contiguous chunk
    const int  bn = wg & 7;
    const long arow0 = bm * BM;
    const long bcol0 = (long)bn * BN;

    const int sr = tid >> 3;           // staging row within half (i adds 64)
    const int ss = tid & 7;            // linear 16B slot

    facc acc[8][4];
#pragma unroll
    for (int i = 0; i < 8; ++i)
#pragma unroll
        for (int j = 0; j < 4; ++j) acc[i][j] = facc{0.f, 0.f, 0.f, 0.f};

    auto stageHalf = [&](int buf, int half, int kt) {
        const long k0 = (long)kt * BK;
#pragma unroll
        for (int i = 0; i < 2; ++i) {
            const int r  = sr + i * 64;
            const int sx = ss ^ (r & 7);                      // inverse swizzle on source
            const u16* src = (half < 2)
                ? (A + (arow0 + half * 128 + r) * (long)FAN + k0 + sx * 8)
                : (W + (bcol0 + (half - 2) * 128 + r) * (long)FAN + k0 + sx * 8);
            gload16(src, &lds[buf][half][i * 4096 + wid * 512]);
        }
    };

    // prologue: K-tile 0 (all 4 halves) -> buf0; K-tile 1 B-halves -> buf1.
    stageHalf(0, 0, 0); stageHalf(0, 1, 0); stageHalf(0, 2, 0); stageHalf(0, 3, 0);
    stageHalf(1, 2, 1); stageHalf(1, 3, 1);
    asm volatile("s_waitcnt vmcnt(4)" ::: "memory");          // tile0 halves complete
    __builtin_amdgcn_s_barrier();

    const u16* Ah[2] = { &lds[0][wm][0],            &lds[1][wm][0] };
    const u16* Bh[2] = { &lds[0][2 + (wn >> 1)][0], &lds[1][2 + (wn >> 1)][0] };
    const int lrB0 = (wn & 1) * 64;

#pragma unroll 1
    for (int t = 0; t < NITER; ++t) {
        const bool pf = (t + 1 < NITER);
        bfrag bq[4][2];
#pragma unroll
        for (int p = 0; p < 8; ++p) {
            const int q  = p & 3;
            const int lt = p >> 2;
            bfrag aq[2][2];
            if (q == 0) {                                     // B-frags once per K-tile
#pragma unroll
                for (int nf = 0; nf < 4; ++nf)
#pragma unroll
                    for (int kk = 0; kk < 2; ++kk) {
                        const int lr = lrB0 + nf * 16 + (lane & 15);
                        const int sl = (kk * 4 + (lane >> 4)) ^ (lane & 7);
                        bq[nf][kk] = *(const bfrag*)(Bh[lt] + lr * 64 + sl * 8);
                    }
            }
#pragma unroll
            for (int m2 = 0; m2 < 2; ++m2)                    // A quadrant (2 M-frags)
#pragma unroll
                for (int kk = 0; kk < 2; ++kk) {
                    const int lr = (q * 2 + m2) * 16 + (lane & 15);
                    const int sl = (kk * 4 + (lane >> 4)) ^ (lane & 7);
                    aq[m2][kk] = *(const bfrag*)(Ah[lt] + lr * 64 + sl * 8);
                }
            // staging schedule: each half staged the phase after its last reader.
            if (p == 0)      stageHalf(1, 0, 2 * t + 1);
            else if (p == 1) stageHalf(1, 1, 2 * t + 1);
            else if (p == 2) { if (pf) stageHalf(0, 2, 2 * t + 2); }
            else if (p == 3) { if (pf) stageHalf(0, 3, 2 * t + 2); }
            else if (p == 4) { if (pf) stageHalf(0, 0, 2 * t + 2); }
            else if (p == 5) { if (pf) stageHalf(0, 1, 2 * t + 2); }
            else if (p == 6) { if (pf) stageHalf(1, 2, 2 * t + 3); }
            else             { if (pf) stageHalf(1, 3, 2 * t + 3); }

            if (q == 0) asm volatile("s_waitcnt lgkmcnt(8)" ::: "memory");
            __builtin_amdgcn_s_barrier();
            asm volatile("s_waitcnt lgkmcnt(0)" ::: "memory");
            __builtin_amdgcn_s_setprio(1);
#pragma unroll
            for (int m2 = 0; m2 < 2; ++m2)
#pragma unroll
                for (int nf = 0; nf < 4; ++nf)
#pragma unroll
                    for (int kk = 0; kk < 2; ++kk)
                        // OPERAND-SWAPPED: D[i=N][j=M]; regs -> 4 consecutive N-cols
                        acc[q * 2 + m2][nf] = __builtin_amdgcn_mfma_f32_16x16x32_bf16(
                            bq[nf][kk], aq[m2][kk], acc[q * 2 + m2][nf], 0, 0, 0);
            __builtin_amdgcn_s_setprio(0);
            if (q == 3) {                                     // counted vmcnt, never mid-loop 0
                if (pf) asm volatile("s_waitcnt vmcnt(4)" ::: "memory");
                else    asm volatile("s_waitcnt vmcnt(0)" ::: "memory");
            }
            __builtin_amdgcn_s_barrier();
        }
    }

    // epilogue: one packed 8B us4 per (mf,nf) -> full 32B sectors, no RMW, no restage.
#pragma unroll
    for (int mf = 0; mf < 8; ++mf)
#pragma unroll
        for (int nf = 0; nf < 4; ++nf) {
            const long m = arow0 + wm * 128 + mf * 16 + (lane & 15);
            const long n = bcol0 + wn * 64 + nf * 16 + ((lane >> 4) << 2);
            us4 pk = { f2b(acc[mf][nf][0]), f2b(acc[mf][nf][1]),
                       f2b(acc[mf][nf][2]), f2b(acc[mf][nf][3]) };
            *(us4*)(Cg + m * (long)NCOL + n) = pk;
        }
}

// ---------------- kernel 2: wave-per-row LN + activations + cell update ----------------
__global__ __launch_bounds__(256)
void lstm_act(const u16* __restrict__ pre, const float* __restrict__ pc,
              const float* __restrict__ bf_, const float* __restrict__ bi_,
              const float* __restrict__ bo_, const float* __restrict__ bj_,
              const float* __restrict__ gf, const float* __restrict__ btf,
              const float* __restrict__ gi, const float* __restrict__ bti,
              const float* __restrict__ go, const float* __restrict__ bto,
              const float* __restrict__ gj, const float* __restrict__ btj,
              const float* __restrict__ gc, const float* __restrict__ btc,
              float* __restrict__ out_h, float* __restrict__ out_c)
{
    const long row  = (long)blockIdx.x * 4 + (threadIdx.x >> 6);
    const int  lane = threadIdx.x & 63;
    const int  c0   = lane * 8;

    const float* bs[4]  = { bf_, bi_, bo_, bj_ };
    const float* gs[4]  = { gf, gi, go, gj };
    const float* bts[4] = { btf, bti, bto, btj };

    float a[4][8];
#pragma unroll
    for (int g = 0; g < 4; ++g) {
        us8 pv = *(const us8*)(pre + row * NCOL + g * HDIM + c0);
        float4 bv0 = *(const float4*)(bs[g] + c0);
        float4 bv1 = *(const float4*)(bs[g] + c0 + 4);
        float bb[8] = { bv0.x, bv0.y, bv0.z, bv0.w, bv1.x, bv1.y, bv1.z, bv1.w };
        float y[8];
        float s = 0.f, ssum = 0.f;
#pragma unroll
        for (int e = 0; e < 8; ++e) {
            y[e] = b2f(pv[e]) + bb[e];
            s += y[e]; ssum += y[e] * y[e];
        }
        float mean, rstd;
        wave_meanrstd(s, ssum, mean, rstd);
        float4 g0 = *(const float4*)(gs[g] + c0);
        float4 g1 = *(const float4*)(gs[g] + c0 + 4);
        float4 t0 = *(const float4*)(bts[g] + c0);
        float4 t1 = *(const float4*)(bts[g] + c0 + 4);
        float gg[8] = { g0.x, g0.y, g0.z, g0.w, g1.x, g1.y, g1.z, g1.w };
        float tt[8] = { t0.x, t0.y, t0.z, t0.w, t1.x, t1.y, t1.z, t1.w };
#pragma unroll
        for (int e = 0; e < 8; ++e) {
            float z = (y[e] - mean) * rstd * gg[e] + tt[e];
            a[g][e] = (g == 3) ? fast_tanh(z) : fast_sigmoid(z);
        }
    }

    float4 p0 = *(const float4*)(pc + row * HDIM + c0);
    float4 p1 = *(const float4*)(pc + row * HDIM + c0 + 4);
    float pcv[8] = { p0.x, p0.y, p0.z, p0.w, p1.x, p1.y, p1.z, p1.w };
    float cr[8];
    float s = 0.f, ssum = 0.f;
#pragma unroll
    for (int e = 0; e < 8; ++e) {
        cr[e] = a[0][e] * pcv[e] + fminf(1.f - a[0][e], a[1][e]) * a[3][e];
        s += cr[e]; ssum += cr[e] * cr[e];
    }
    float mean, rstd;
    wave_meanrstd(s, ssum, mean, rstd);
    float4 gc0 = *(const float4*)(gc + c0);
    float4 gc1 = *(const float4*)(gc + c0 + 4);
    float4 tc0 = *(const float4*)(btc + c0);
    float4 tc1 = *(const float4*)(btc + c0 + 4);
    float gg[8] = { gc0.x, gc0.y, gc0.z, gc0.w, gc1.x, gc1.y, gc1.z, gc1.w };
    float tt[8] = { tc0.x, tc0.y, tc0.z, tc0.w, tc1.x, tc1.y, tc1.z, tc1.w };
    float hv[8], cv[8];
#pragma unroll
    for (int e = 0; e < 8; ++e) {
        float cc = (cr[e] - mean) * rstd * gg[e] + tt[e];
        cv[e] = cc;
        hv[e] = a[2][e] * cc;
    }
    *(float4*)(out_h + row * HDIM + c0)     = make_float4(hv[0], hv[1], hv[2], hv[3]);
    *(float4*)(out_h + row * HDIM + c0 + 4) = make_float4(hv[4], hv[5], hv[6], hv[7]);
    *(float4*)(out_c + row * HDIM + c0)     = make_float4(cv[0], cv[1], cv[2], cv[3]);
    *(float4*)(out_c + row * HDIM + c0 + 4) = make_float4(cv[4], cv[5], cv[6], cv[7]);
}

// ---------------- fallback (only if ws too small): fp32 naive, no workspace ----------------
static __device__ __forceinline__ void ln_pair(
    float y0, float y1,
    const float* __restrict__ gam, const float* __restrict__ bet, int c0,
    float* red, int lane, int wid, float& o0, float& o1)
{
    float s = y0 + y1, ss = y0 * y0 + y1 * y1;
#pragma unroll
    for (int o = 32; o; o >>= 1) { s += __shfl_down(s, o); ss += __shfl_down(ss, o); }
    if (lane == 0) { red[wid * 2] = s; red[wid * 2 + 1] = ss; }
    __syncthreads();
    float S  = red[0] + red[2] + red[4] + red[6];
    float SS = red[1] + red[3] + red[5] + red[7];
    __syncthreads();
    float mean = S * (1.f / 512.f);
    float var  = (SS - 512.f * mean * mean) * (1.f / 511.f);
    float rstd = 1.f / (sqrtf(fmaxf(var, 0.f)) + EPS);
    o0 = (y0 - mean) * rstd * gam[c0]     + bet[c0];
    o1 = (y1 - mean) * rstd * gam[c0 + 1] + bet[c0 + 1];
}

__global__ __launch_bounds__(256)
void lstm_naive(const float* __restrict__ x, const float* __restrict__ ph, const float* __restrict__ pc,
                const float* __restrict__ Wf, const float* __restrict__ bf_,
                const float* __restrict__ Wi, const float* __restrict__ bi_,
                const float* __restrict__ Wo, const float* __restrict__ bo_,
                const float* __restrict__ Wj, const float* __restrict__ bj_,
                const float* __restrict__ gf, const float* __restrict__ btf,
                const float* __restrict__ gi, const float* __restrict__ bti,
                const float* __restrict__ go, const float* __restrict__ bto,
                const float* __restrict__ gj, const float* __restrict__ btj,
                const float* __restrict__ gc, const float* __restrict__ btc,
                float* __restrict__ out_h, float* __restrict__ out_c)
{
    __shared__ float comb[FAN];
    __shared__ float red[8];
    const int b = blockIdx.x, t = threadIdx.x;
    const int lane = t & 63, wid = t >> 6;
    for (int k = t; k < D_IN; k += 256) {
        comb[k]        = x[(long)b * D_IN + k];
        comb[D_IN + k] = ph[(long)b * HDIM + k];
    }
    __syncthreads();
    const int c0 = t * 2;
    const float* Ws[4]  = { Wf, Wi, Wo, Wj };
    const float* bs[4]  = { bf_, bi_, bo_, bj_ };
    const float* gs[4]  = { gf, gi, go, gj };
    const float* bts[4] = { btf, bti, bto, btj };
    float a[4][2];
#pragma unroll
    for (int g = 0; g < 4; ++g) {
        float y[2];
#pragma unroll
        for (int e = 0; e < 2; ++e) {
            const float4* w4 = (const float4*)(Ws[g] + (long)(c0 + e) * FAN);
            const float4* c4 = (const float4*)comb;
            float s = 0.f;
            for (int k = 0; k < FAN / 4; ++k) {
                float4 wv = w4[k], cv = c4[k];
                s += wv.x * cv.x + wv.y * cv.y + wv.z * cv.z + wv.w * cv.w;
            }
            y[e] = s + bs[g][c0 + e];
        }
        ln_pair(y[0], y[1], gs[g], bts[g], c0, red, lane, wid, a[g][0], a[g][1]);
        if (g == 3) { a[g][0] = tanhf(a[g][0]); a[g][1] = tanhf(a[g][1]); }
        else        { a[g][0] = 1.f / (1.f + expf(-a[g][0]));
                      a[g][1] = 1.f / (1.f + expf(-a[g][1])); }
    }
    float2 pcv = *(const float2*)(pc + (long)b * HDIM + c0);
    float f0 = a[0][0], i0 = a[1][0], o0 = a[2][0], j0 = a[3][0];
    float f1 = a[0][1], i1 = a[1][1], o1 = a[2][1], j1 = a[3][1];
    float cr0 = f0 * pcv.x + fminf(1.f - f0, i0) * j0;
    float cr1 = f1 * pcv.y + fminf(1.f - f1, i1) * j1;
    float cc0, cc1;
    ln_pair(cr0, cr1, gc, btc, c0, red, lane, wid, cc0, cc1);
    *(float2*)(out_h + (long)b * HDIM + c0) = make_float2(o0 * cc0, o1 * cc1);
    *(float2*)(out_c + (long)b * HDIM + c0) = make_float2(cc0, cc1);
}

// ---------------- launcher ----------------
extern "C" void kernel_launch(void* const* d_in, const int* in_sizes, int n_in,
                              void* d_out, int out_size, void* d_ws, size_t ws_size,
                              hipStream_t stream)
{
    const float* x   = (const float*)d_in[0];
    const float* ph  = (const float*)d_in[1];
    const float* pc  = (const float*)d_in[2];
    const float* Wf  = (const float*)d_in[3];
    const float* bf_ = (const float*)d_in[4];
    const float* Wi  = (const float*)d_in[5];
    const float* bi_ = (const float*)d_in[6];
    const float* Wo  = (const float*)d_in[7];
    const float* bo_ = (const float*)d_in[8];
    const float* Wj  = (const float*)d_in[9];
    const float* bj_ = (const float*)d_in[10];
    const float* gf  = (const float*)d_in[11];
    const float* btf = (const float*)d_in[12];
    const float* gi  = (const float*)d_in[13];
    const float* bti = (const float*)d_in[14];
    const float* go  = (const float*)d_in[15];
    const float* bto = (const float*)d_in[16];
    const float* gj  = (const float*)d_in[17];
    const float* btj = (const float*)d_in[18];
    const float* gc  = (const float*)d_in[19];
    const float* btc = (const float*)d_in[20];
    float* out_h = (float*)d_out;
    float* out_c = out_h + (size_t)B_ROWS * HDIM;

    const size_t combElems  = (size_t)B_ROWS * FAN;
    const size_t wElems     = (size_t)NCOL * FAN;
    const size_t fixedBytes = (combElems + wElems) * 2;

    long slabRows = 0;
    if (ws_size > fixedBytes) {
        size_t avail = ws_size - fixedBytes;
        slabRows = (long)(avail / ((size_t)NCOL * 2));
        slabRows &= ~255L;                                  // multiple of BM=256
        if (slabRows > B_ROWS) slabRows = B_ROWS;
    }

    if (slabRows >= 256) {
        u16* comb = (u16*)d_ws;
        u16* Wall = comb + combElems;
        u16* pre  = Wall + wElems;
        pack_combined<<<dim3((unsigned)((B_ROWS * (long)D_IN / 4 + 255) / 256)), dim3(256), 0, stream>>>(x, ph, comb);
        pack_w<<<dim3((unsigned)(((long)NCOL * FAN / 4 + 255) / 256)), dim3(256), 0, stream>>>(Wf, Wi, Wo, Wj, Wall);
        for (long r0 = 0; r0 < B_ROWS; r0 += slabRows) {
            long rows = B_ROWS - r0; if (rows > slabRows) rows = slabRows;
            const unsigned nwg = (unsigned)((rows / BM) * (NCOL / BN));   // n-fastest, %8==0
            gemm_gates<<<dim3(nwg), dim3(512), 0, stream>>>(comb + r0 * FAN, Wall, pre);
            lstm_act<<<dim3((unsigned)(rows / 4)), dim3(256), 0, stream>>>(
                pre, pc + r0 * HDIM,
                bf_, bi_, bo_, bj_,
                gf, btf, gi, bti, go, bto, gj, btj, gc, btc,
                out_h + r0 * HDIM, out_c + r0 * HDIM);
        }
    } else {
        lstm_naive<<<dim3(B_ROWS), dim3(256), 0, stream>>>(
            x, ph, pc, Wf, bf_, Wi, bi_, Wo, bo_, Wj, bj_,
            gf, btf, gi, bti, go, bto, gj, btj, gc, btc, out_h, out_c);
    }
}

// Round 9
// 561.493 us; speedup vs baseline: 1.0032x; 1.0032x over previous
//
#include <hip/hip_runtime.h>
#include <math.h>

// ---------------- problem constants ----------------
#define B_ROWS 65536
#define D_IN   512
#define HDIM   512
#define FAN    1024          // D_IN + HDIM
#define NCOL   2048          // 4 gates * HDIM
#define EPS    1e-5f

// GEMM tile (256^2 8-phase, persistent-lite: 4 N-tiles per block)
#define BM 256
#define BN 256
#define BK 64
#define KTILES (FAN / BK)    // 16 per output tile
#define NITER  (KTILES / 2)  // 8 iterations, 2 K-tiles each
#define TILES_PER_BLK 4      // N-tiles per block (half of NCOL/BN)

typedef unsigned short u16;
using bfrag = __attribute__((ext_vector_type(8))) short;          // 8 bf16 (4 VGPRs)
using facc  = __attribute__((ext_vector_type(4))) float;          // 4 fp32 acc
using us4   = __attribute__((ext_vector_type(4))) unsigned short;
using us8   = __attribute__((ext_vector_type(8))) unsigned short;

// ---------------- helpers ----------------
static __device__ __forceinline__ u16 f2b(float f) {              // fp32 -> bf16 RNE
    unsigned u = __builtin_bit_cast(unsigned, f);
    u += 0x7fffu + ((u >> 16) & 1u);
    return (u16)(u >> 16);
}
static __device__ __forceinline__ float b2f(u16 h) {
    unsigned u = ((unsigned)h) << 16;
    return __builtin_bit_cast(float, u);
}
static __device__ __forceinline__ void gload16(const u16* g, u16* l) {
    __builtin_amdgcn_global_load_lds(
        (const __attribute__((address_space(1))) void*)g,
        (__attribute__((address_space(3))) void*)l, 16, 0, 0);
}
static __device__ __forceinline__ void wave_meanrstd(float s, float ss, float& mean, float& rstd)
{
#pragma unroll
    for (int o = 1; o < 64; o <<= 1) { s += __shfl_xor(s, o); ss += __shfl_xor(ss, o); }
    mean = s * (1.f / 512.f);
    float var = (ss - 512.f * mean * mean) * (1.f / 511.f);
    rstd = 1.f / (sqrtf(fmaxf(var, 0.f)) + EPS);
}
static __device__ __forceinline__ float fast_sigmoid(float z) {
    return __fdividef(1.f, 1.f + __expf(-z));
}
static __device__ __forceinline__ float fast_tanh(float z) {
    return __fdividef(2.f, 1.f + __expf(-2.f * z)) - 1.f;
}

// ---------------- kernel 0a: pack combined = concat(x, prev_h) as bf16 ----------------
__global__ void pack_combined(const float* __restrict__ x, const float* __restrict__ ph,
                              u16* __restrict__ comb)
{
    long i = (long)blockIdx.x * 256 + threadIdx.x;
    if (i >= (long)B_ROWS * D_IN / 4) return;
    long e = i * 4;
    long b = e >> 9;
    int  d = (int)(e & 511);
    float4 xv = *(const float4*)(x + e);
    float4 hv = *(const float4*)(ph + e);
    us4 xb = { f2b(xv.x), f2b(xv.y), f2b(xv.z), f2b(xv.w) };
    us4 hb = { f2b(hv.x), f2b(hv.y), f2b(hv.z), f2b(hv.w) };
    *(us4*)(comb + b * FAN + d)        = xb;
    *(us4*)(comb + b * FAN + D_IN + d) = hb;
}

// ---------------- kernel 0b: pack W = [Wf;Wi;Wo;Wj] as bf16 [2048][1024] ----------------
__global__ void pack_w(const float* __restrict__ Wf, const float* __restrict__ Wi,
                       const float* __restrict__ Wo, const float* __restrict__ Wj,
                       u16* __restrict__ Wall)
{
    long i = (long)blockIdx.x * 256 + threadIdx.x;
    if (i >= (long)NCOL * FAN / 4) return;
    long e = i * 4;
    int  g = (int)(e >> 19);
    long rem = e & 524287L;
    const float* src = (g == 0) ? Wf : (g == 1) ? Wi : (g == 2) ? Wo : Wj;
    float4 v = *(const float4*)(src + rem);
    us4 p = { f2b(v.x), f2b(v.y), f2b(v.z), f2b(v.w) };
    *(us4*)(Wall + e) = p;
}

// ---------------- kernel 0c: pack bias = [bf;bi;bo;bj] as f32 [2048] ----------------
__global__ void pack_bias(const float* __restrict__ bf_, const float* __restrict__ bi_,
                          const float* __restrict__ bo_, const float* __restrict__ bj_,
                          float* __restrict__ biasAll)
{
    int idx = blockIdx.x * 256 + threadIdx.x;
    if (idx >= NCOL) return;
    int g = idx >> 9;
    const float* s = (g == 0) ? bf_ : (g == 1) ? bi_ : (g == 2) ? bo_ : bj_;
    biasAll[idx] = s[idx & 511];
}

// ---------------- kernel 1: persistent-lite 256^2 8-phase GEMM + bias ------------------
// Grid = mtiles*2 blocks; each block: fixed bm (A-panel reused), loops 4 N-tiles.
// Continuous staging pipeline across tile boundaries (round-6 schedule, verified).
// OPERAND-SWAPPED mfma (round-8, verified): D col=lane&15 -> M, regs -> 4 consecutive
// N-cols, so the epilogue is one packed 8B us4 store per (mf,nf): full 32B sectors,
// no L2 read-modify-write, no LDS restage, zero bank conflicts. Bias added in fp32.
__global__ __launch_bounds__(512)
void gemm_gates(const u16* __restrict__ A, const u16* __restrict__ W,
                const float* __restrict__ biasAll, u16* __restrict__ Cg)
{
    __shared__ u16 lds[2][4][8192];

    const int tid  = threadIdx.x;
    const int lane = tid & 63;
    const int wid  = tid >> 6;
    const int wm   = wid >> 2;         // 0..1
    const int wn   = wid & 3;          // 0..3

    // XCD-aware bijective swizzle (nwg = mtiles*2, always a multiple of 8)
    const int nwg = gridDim.x;
    const int swz = (blockIdx.x & 7) * (nwg >> 3) + (blockIdx.x >> 3);
    const long bm  = swz >> 1;
    const int  bn4 = (swz & 1) * TILES_PER_BLK;     // first N-tile: 0 or 4
    const long arow0 = bm * BM;

    const int sr = tid >> 3;           // staging row within half (i adds 64)
    const int ss = tid & 7;            // linear 16B slot

    facc acc[8][4];
#pragma unroll
    for (int i = 0; i < 8; ++i)
#pragma unroll
        for (int j = 0; j < 4; ++j) acc[i][j] = facc{0.f, 0.f, 0.f, 0.f};

    auto stageHalf = [&](int buf, int half, int ktg) {
        if (ktg >= TILES_PER_BLK * KTILES) ktg = 0;           // dummy: valid addr, never read
        const long k0    = (long)(ktg & (KTILES - 1)) * BK;
        const long bcol0 = ((long)bn4 + (ktg >> 4)) * BN;     // N-tile for this K-chunk
#pragma unroll
        for (int i = 0; i < 2; ++i) {
            const int r  = sr + i * 64;
            const int sx = ss ^ (r & 7);                      // inverse swizzle on source
            const u16* src = (half < 2)
                ? (A + (arow0 + half * 128 + r) * (long)FAN + k0 + sx * 8)
                : (W + (bcol0 + (half - 2) * 128 + r) * (long)FAN + k0 + sx * 8);
            gload16(src, &lds[buf][half][i * 4096 + wid * 512]);
        }
    };

    // prologue: K-tile 0 (all 4 halves) -> buf0; K-tile 1 B-halves -> buf1.
    stageHalf(0, 0, 0); stageHalf(0, 1, 0); stageHalf(0, 2, 0); stageHalf(0, 3, 0);
    stageHalf(1, 2, 1); stageHalf(1, 3, 1);
    asm volatile("s_waitcnt vmcnt(4)" ::: "memory");
    __builtin_amdgcn_s_barrier();

    const u16* Ah[2] = { &lds[0][wm][0],            &lds[1][wm][0] };
    const u16* Bh[2] = { &lds[0][2 + (wn >> 1)][0], &lds[1][2 + (wn >> 1)][0] };
    const int lrB0 = (wn & 1) * 64;

#pragma unroll 1
    for (int tile = 0; tile < TILES_PER_BLK; ++tile) {
        const int kb = tile * KTILES;
#pragma unroll 1
        for (int t = 0; t < NITER; ++t) {
            bfrag bq[4][2];
#pragma unroll
            for (int p = 0; p < 8; ++p) {
                const int q  = p & 3;
                const int lt = p >> 2;
                bfrag aq[2][2];
                if (q == 0) {                                 // B-frags once per K-tile
#pragma unroll
                    for (int nf = 0; nf < 4; ++nf)
#pragma unroll
                        for (int kk = 0; kk < 2; ++kk) {
                            const int lr = lrB0 + nf * 16 + (lane & 15);
                            const int sl = (kk * 4 + (lane >> 4)) ^ (lane & 7);
                            bq[nf][kk] = *(const bfrag*)(Bh[lt] + lr * 64 + sl * 8);
                        }
                }
#pragma unroll
                for (int m2 = 0; m2 < 2; ++m2)                // A quadrant (2 M-frags)
#pragma unroll
                    for (int kk = 0; kk < 2; ++kk) {
                        const int lr = (q * 2 + m2) * 16 + (lane & 15);
                        const int sl = (kk * 4 + (lane >> 4)) ^ (lane & 7);
                        aq[m2][kk] = *(const bfrag*)(Ah[lt] + lr * 64 + sl * 8);
                    }
                // continuous staging schedule (uniform; dummies clamp past the end)
                if (p == 0)      stageHalf(1, 0, kb + 2 * t + 1);
                else if (p == 1) stageHalf(1, 1, kb + 2 * t + 1);
                else if (p == 2) stageHalf(0, 2, kb + 2 * t + 2);
                else if (p == 3) stageHalf(0, 3, kb + 2 * t + 2);
                else if (p == 4) stageHalf(0, 0, kb + 2 * t + 2);
                else if (p == 5) stageHalf(0, 1, kb + 2 * t + 2);
                else if (p == 6) stageHalf(1, 2, kb + 2 * t + 3);
                else             stageHalf(1, 3, kb + 2 * t + 3);

                if (q == 0) asm volatile("s_waitcnt lgkmcnt(8)" ::: "memory");
                __builtin_amdgcn_s_barrier();
                asm volatile("s_waitcnt lgkmcnt(0)" ::: "memory");
                __builtin_amdgcn_s_setprio(1);
#pragma unroll
                for (int m2 = 0; m2 < 2; ++m2)
#pragma unroll
                    for (int nf = 0; nf < 4; ++nf)
#pragma unroll
                        for (int kk = 0; kk < 2; ++kk)
                            // OPERAND-SWAPPED: D[i=N][j=M]; regs -> 4 consecutive N-cols
                            acc[q * 2 + m2][nf] = __builtin_amdgcn_mfma_f32_16x16x32_bf16(
                                bq[nf][kk], aq[m2][kk], acc[q * 2 + m2][nf], 0, 0, 0);
                __builtin_amdgcn_s_setprio(0);
                if (q == 3) asm volatile("s_waitcnt vmcnt(4)" ::: "memory");  // counted, never 0
                __builtin_amdgcn_s_barrier();
            }
        }

        // epilogue for this tile: bias + one packed 8B us4 per (mf,nf); full 32B
        // sectors (lanes l,l+16,l+32,l+48 cover n..n+15), no RMW. Stores drain
        // under the next tile's early phases (counted vmcnt never hits 0 mid-loop).
        const long bcol0 = ((long)bn4 + tile) * BN;
#pragma unroll
        for (int nf = 0; nf < 4; ++nf) {
            const long n = bcol0 + wn * 64 + nf * 16 + ((lane >> 4) << 2);
            float4 bv = *(const float4*)(biasAll + n);
#pragma unroll
            for (int mf = 0; mf < 8; ++mf) {
                const long m = arow0 + wm * 128 + mf * 16 + (lane & 15);
                us4 pk = { f2b(acc[mf][nf][0] + bv.x), f2b(acc[mf][nf][1] + bv.y),
                           f2b(acc[mf][nf][2] + bv.z), f2b(acc[mf][nf][3] + bv.w) };
                *(us4*)(Cg + m * (long)NCOL + n) = pk;
                acc[mf][nf] = facc{0.f, 0.f, 0.f, 0.f};
            }
        }
    }
}

// ---------------- kernel 2: grid-stride LN + activations, params register-resident ----
// Each wave handles rows/(grid*4) rows; the 10 gamma/beta arrays (bias folded into
// GEMM) are loaded ONCE per wave into VGPRs instead of per row (was 448 B/lane/row
// of broadcast reloads -> act ran at 55% of BW floor).
__global__ __launch_bounds__(256)
void lstm_act(const u16* __restrict__ pre, const float* __restrict__ pc,
              const float* __restrict__ gf, const float* __restrict__ btf,
              const float* __restrict__ gi, const float* __restrict__ bti,
              const float* __restrict__ go, const float* __restrict__ bto,
              const float* __restrict__ gj, const float* __restrict__ btj,
              const float* __restrict__ gc, const float* __restrict__ btc,
              float* __restrict__ out_h, float* __restrict__ out_c, long rows)
{
    const int  lane = threadIdx.x & 63;
    const int  c0   = lane * 8;
    const long wave = (long)blockIdx.x * 4 + (threadIdx.x >> 6);
    const long totW = (long)gridDim.x * 4;

    const float* gs[4]  = { gf, gi, go, gj };
    const float* bts[4] = { btf, bti, bto, btj };
    float gg[4][8], tt[4][8], gcv[8], tcv[8];
#pragma unroll
    for (int g = 0; g < 4; ++g) {
        *(float4*)&gg[g][0] = *(const float4*)(gs[g] + c0);
        *(float4*)&gg[g][4] = *(const float4*)(gs[g] + c0 + 4);
        *(float4*)&tt[g][0] = *(const float4*)(bts[g] + c0);
        *(float4*)&tt[g][4] = *(const float4*)(bts[g] + c0 + 4);
    }
    *(float4*)&gcv[0] = *(const float4*)(gc + c0);
    *(float4*)&gcv[4] = *(const float4*)(gc + c0 + 4);
    *(float4*)&tcv[0] = *(const float4*)(btc + c0);
    *(float4*)&tcv[4] = *(const float4*)(btc + c0 + 4);

#pragma unroll 1
    for (long row = wave; row < rows; row += totW) {
        float a4[4][8];
#pragma unroll
        for (int g = 0; g < 4; ++g) {
            us8 pv = *(const us8*)(pre + row * NCOL + g * HDIM + c0);
            float y[8];
            float s = 0.f, ssum = 0.f;
#pragma unroll
            for (int e = 0; e < 8; ++e) {
                y[e] = b2f(pv[e]);                 // bias already added in GEMM
                s += y[e]; ssum += y[e] * y[e];
            }
            float mean, rstd;
            wave_meanrstd(s, ssum, mean, rstd);
#pragma unroll
            for (int e = 0; e < 8; ++e) {
                float z = (y[e] - mean) * rstd * gg[g][e] + tt[g][e];
                a4[g][e] = (g == 3) ? fast_tanh(z) : fast_sigmoid(z);
            }
        }

        float4 p0 = *(const float4*)(pc + row * HDIM + c0);
        float4 p1 = *(const float4*)(pc + row * HDIM + c0 + 4);
        float pcv[8] = { p0.x, p0.y, p0.z, p0.w, p1.x, p1.y, p1.z, p1.w };
        float cr[8];
        float s = 0.f, ssum = 0.f;
#pragma unroll
        for (int e = 0; e < 8; ++e) {
            cr[e] = a4[0][e] * pcv[e] + fminf(1.f - a4[0][e], a4[1][e]) * a4[3][e];
            s += cr[e]; ssum += cr[e] * cr[e];
        }
        float mean, rstd;
        wave_meanrstd(s, ssum, mean, rstd);
        float hv[8], cv[8];
#pragma unroll
        for (int e = 0; e < 8; ++e) {
            float cc = (cr[e] - mean) * rstd * gcv[e] + tcv[e];
            cv[e] = cc;
            hv[e] = a4[2][e] * cc;
        }
        *(float4*)(out_h + row * HDIM + c0)     = make_float4(hv[0], hv[1], hv[2], hv[3]);
        *(float4*)(out_h + row * HDIM + c0 + 4) = make_float4(hv[4], hv[5], hv[6], hv[7]);
        *(float4*)(out_c + row * HDIM + c0)     = make_float4(cv[0], cv[1], cv[2], cv[3]);
        *(float4*)(out_c + row * HDIM + c0 + 4) = make_float4(cv[4], cv[5], cv[6], cv[7]);
    }
}

// ---------------- fallback (only if ws too small): fp32 naive, no workspace ----------------
static __device__ __forceinline__ void ln_pair(
    float y0, float y1,
    const float* __restrict__ gam, const float* __restrict__ bet, int c0,
    float* red, int lane, int wid, float& o0, float& o1)
{
    float s = y0 + y1, ss = y0 * y0 + y1 * y1;
#pragma unroll
    for (int o = 32; o; o >>= 1) { s += __shfl_down(s, o); ss += __shfl_down(ss, o); }
    if (lane == 0) { red[wid * 2] = s; red[wid * 2 + 1] = ss; }
    __syncthreads();
    float S  = red[0] + red[2] + red[4] + red[6];
    float SS = red[1] + red[3] + red[5] + red[7];
    __syncthreads();
    float mean = S * (1.f / 512.f);
    float var  = (SS - 512.f * mean * mean) * (1.f / 511.f);
    float rstd = 1.f / (sqrtf(fmaxf(var, 0.f)) + EPS);
    o0 = (y0 - mean) * rstd * gam[c0]     + bet[c0];
    o1 = (y1 - mean) * rstd * gam[c0 + 1] + bet[c0 + 1];
}

__global__ __launch_bounds__(256)
void lstm_naive(const float* __restrict__ x, const float* __restrict__ ph, const float* __restrict__ pc,
                const float* __restrict__ Wf, const float* __restrict__ bf_,
                const float* __restrict__ Wi, const float* __restrict__ bi_,
                const float* __restrict__ Wo, const float* __restrict__ bo_,
                const float* __restrict__ Wj, const float* __restrict__ bj_,
                const float* __restrict__ gf, const float* __restrict__ btf,
                const float* __restrict__ gi, const float* __restrict__ bti,
                const float* __restrict__ go, const float* __restrict__ bto,
                const float* __restrict__ gj, const float* __restrict__ btj,
                const float* __restrict__ gc, const float* __restrict__ btc,
                float* __restrict__ out_h, float* __restrict__ out_c)
{
    __shared__ float comb[FAN];
    __shared__ float red[8];
    const int b = blockIdx.x, t = threadIdx.x;
    const int lane = t & 63, wid = t >> 6;
    for (int k = t; k < D_IN; k += 256) {
        comb[k]        = x[(long)b * D_IN + k];
        comb[D_IN + k] = ph[(long)b * HDIM + k];
    }
    __syncthreads();
    const int c0 = t * 2;
    const float* Ws[4]  = { Wf, Wi, Wo, Wj };
    const float* bs[4]  = { bf_, bi_, bo_, bj_ };
    const float* gs[4]  = { gf, gi, go, gj };
    const float* bts[4] = { btf, bti, bto, btj };
    float a[4][2];
#pragma unroll
    for (int g = 0; g < 4; ++g) {
        float y[2];
#pragma unroll
        for (int e = 0; e < 2; ++e) {
            const float4* w4 = (const float4*)(Ws[g] + (long)(c0 + e) * FAN);
            const float4* c4 = (const float4*)comb;
            float s = 0.f;
            for (int k = 0; k < FAN / 4; ++k) {
                float4 wv = w4[k], cv = c4[k];
                s += wv.x * cv.x + wv.y * cv.y + wv.z * cv.z + wv.w * cv.w;
            }
            y[e] = s + bs[g][c0 + e];
        }
        ln_pair(y[0], y[1], gs[g], bts[g], c0, red, lane, wid, a[g][0], a[g][1]);
        if (g == 3) { a[g][0] = tanhf(a[g][0]); a[g][1] = tanhf(a[g][1]); }
        else        { a[g][0] = 1.f / (1.f + expf(-a[g][0]));
                      a[g][1] = 1.f / (1.f + expf(-a[g][1])); }
    }
    float2 pcv = *(const float2*)(pc + (long)b * HDIM + c0);
    float f0 = a[0][0], i0 = a[1][0], o0 = a[2][0], j0 = a[3][0];
    float f1 = a[0][1], i1 = a[1][1], o1 = a[2][1], j1 = a[3][1];
    float cr0 = f0 * pcv.x + fminf(1.f - f0, i0) * j0;
    float cr1 = f1 * pcv.y + fminf(1.f - f1, i1) * j1;
    float cc0, cc1;
    ln_pair(cr0, cr1, gc, btc, c0, red, lane, wid, cc0, cc1);
    *(float2*)(out_h + (long)b * HDIM + c0) = make_float2(o0 * cc0, o1 * cc1);
    *(float2*)(out_c + (long)b * HDIM + c0) = make_float2(cc0, cc1);
}

// ---------------- launcher ----------------
extern "C" void kernel_launch(void* const* d_in, const int* in_sizes, int n_in,
                              void* d_out, int out_size, void* d_ws, size_t ws_size,
                              hipStream_t stream)
{
    const float* x   = (const float*)d_in[0];
    const float* ph  = (const float*)d_in[1];
    const float* pc  = (const float*)d_in[2];
    const float* Wf  = (const float*)d_in[3];
    const float* bf_ = (const float*)d_in[4];
    const float* Wi  = (const float*)d_in[5];
    const float* bi_ = (const float*)d_in[6];
    const float* Wo  = (const float*)d_in[7];
    const float* bo_ = (const float*)d_in[8];
    const float* Wj  = (const float*)d_in[9];
    const float* bj_ = (const float*)d_in[10];
    const float* gf  = (const float*)d_in[11];
    const float* btf = (const float*)d_in[12];
    const float* gi  = (const float*)d_in[13];
    const float* bti = (const float*)d_in[14];
    const float* go  = (const float*)d_in[15];
    const float* bto = (const float*)d_in[16];
    const float* gj  = (const float*)d_in[17];
    const float* btj = (const float*)d_in[18];
    const float* gc  = (const float*)d_in[19];
    const float* btc = (const float*)d_in[20];
    float* out_h = (float*)d_out;
    float* out_c = out_h + (size_t)B_ROWS * HDIM;

    const size_t combElems  = (size_t)B_ROWS * FAN;            // bf16
    const size_t wElems     = (size_t)NCOL * FAN;              // bf16
    const size_t biasBytes  = (size_t)NCOL * sizeof(float);    // 8 KB
    const size_t fixedBytes = (combElems + wElems) * 2 + biasBytes;

    long slabRows = 0;
    if (ws_size > fixedBytes) {
        size_t avail = ws_size - fixedBytes;
        slabRows = (long)(avail / ((size_t)NCOL * 2));
        slabRows &= ~1023L;                                 // grid = (rows/256)*2 must be %8
        if (slabRows > B_ROWS) slabRows = B_ROWS;
    }

    if (slabRows >= 1024) {
        u16*   comb    = (u16*)d_ws;
        u16*   Wall    = comb + combElems;
        float* biasAll = (float*)(Wall + wElems);
        u16*   pre     = (u16*)(biasAll + NCOL);
        pack_combined<<<dim3((unsigned)((B_ROWS * (long)D_IN / 4 + 255) / 256)), dim3(256), 0, stream>>>(x, ph, comb);
        pack_w<<<dim3((unsigned)(((long)NCOL * FAN / 4 + 255) / 256)), dim3(256), 0, stream>>>(Wf, Wi, Wo, Wj, Wall);
        pack_bias<<<dim3(8), dim3(256), 0, stream>>>(bf_, bi_, bo_, bj_, biasAll);
        for (long r0 = 0; r0 < B_ROWS; r0 += slabRows) {
            long rows = B_ROWS - r0; if (rows > slabRows) rows = slabRows;
            const unsigned nwg = (unsigned)((rows / BM) * 2);   // 2 blocks per M-tile (4 N-tiles each)
            gemm_gates<<<dim3(nwg), dim3(512), 0, stream>>>(comb + r0 * FAN, Wall, biasAll, pre);
            lstm_act<<<dim3(1024), dim3(256), 0, stream>>>(
                pre, pc + r0 * HDIM,
                gf, btf, gi, bti, go, bto, gj, btj, gc, btc,
                out_h + r0 * HDIM, out_c + r0 * HDIM, rows);
        }
    } else {
        lstm_naive<<<dim3(B_ROWS), dim3(256), 0, stream>>>(
            x, ph, pc, Wf, bf_, Wi, bi_, Wo, bo_, Wj, bj_,
            gf, btf, gi, bti, go, bto, gj, btj, gc, btc, out_h, out_c);
    }
}

// Round 11
// 559.303 us; speedup vs baseline: 1.0071x; 1.0039x over previous
//
#include <hip/hip_runtime.h>
#include <math.h>

// ---------------- problem constants ----------------
#define B_ROWS 65536
#define D_IN   512
#define HDIM   512
#define FAN    1024          // D_IN + HDIM
#define NCOL   2048          // 4 gates * HDIM
#define EPS    1e-5f

// GEMM tile (256^2 8-phase, persistent-lite: 4 N-tiles per block), 32x32x16 MFMA
#define BM 256
#define BN 256
#define BK 64
#define KTILES (FAN / BK)    // 16 per output tile
#define NITER  (KTILES / 2)  // 8 iterations, 2 K-tiles each
#define TILES_PER_BLK 4      // N-tiles per block (half of NCOL/BN)

typedef unsigned short u16;
using bfrag  = __attribute__((ext_vector_type(8))) short;         // 8 bf16 (4 VGPRs)
using facc16 = __attribute__((ext_vector_type(16))) float;        // 32x32 accumulator
using us4    = __attribute__((ext_vector_type(4))) unsigned short;
using us8    = __attribute__((ext_vector_type(8))) unsigned short;
using f4v    = __attribute__((ext_vector_type(4))) float;         // clang vec for nontemporal

// ---------------- helpers ----------------
static __device__ __forceinline__ u16 f2b(float f) {              // fp32 -> bf16 RNE
    unsigned u = __builtin_bit_cast(unsigned, f);
    u += 0x7fffu + ((u >> 16) & 1u);
    return (u16)(u >> 16);
}
static __device__ __forceinline__ float b2f(u16 h) {
    unsigned u = ((unsigned)h) << 16;
    return __builtin_bit_cast(float, u);
}
static __device__ __forceinline__ void gload16(const u16* g, u16* l) {
    __builtin_amdgcn_global_load_lds(
        (const __attribute__((address_space(1))) void*)g,
        (__attribute__((address_space(3))) void*)l, 16, 0, 0);
}
static __device__ __forceinline__ void wave_meanrstd(float s, float ss, float& mean, float& rstd)
{
#pragma unroll
    for (int o = 1; o < 64; o <<= 1) { s += __shfl_xor(s, o); ss += __shfl_xor(ss, o); }
    mean = s * (1.f / 512.f);
    float var = (ss - 512.f * mean * mean) * (1.f / 511.f);
    rstd = 1.f / (sqrtf(fmaxf(var, 0.f)) + EPS);
}
static __device__ __forceinline__ float fast_sigmoid(float z) {
    return __fdividef(1.f, 1.f + __expf(-z));
}
static __device__ __forceinline__ float fast_tanh(float z) {
    return __fdividef(2.f, 1.f + __expf(-2.f * z)) - 1.f;
}

// ---------------- kernel 0a: pack combined = concat(x, prev_h) as bf16 ----------------
__global__ void pack_combined(const float* __restrict__ x, const float* __restrict__ ph,
                              u16* __restrict__ comb)
{
    long i = (long)blockIdx.x * 256 + threadIdx.x;
    if (i >= (long)B_ROWS * D_IN / 4) return;
    long e = i * 4;
    long b = e >> 9;
    int  d = (int)(e & 511);
    float4 xv = *(const float4*)(x + e);
    float4 hv = *(const float4*)(ph + e);
    us4 xb = { f2b(xv.x), f2b(xv.y), f2b(xv.z), f2b(xv.w) };
    us4 hb = { f2b(hv.x), f2b(hv.y), f2b(hv.z), f2b(hv.w) };
    *(us4*)(comb + b * FAN + d)        = xb;
    *(us4*)(comb + b * FAN + D_IN + d) = hb;
}

// ---------------- kernel 0b: pack W = [Wf;Wi;Wo;Wj] as bf16 [2048][1024] ----------------
__global__ void pack_w(const float* __restrict__ Wf, const float* __restrict__ Wi,
                       const float* __restrict__ Wo, const float* __restrict__ Wj,
                       u16* __restrict__ Wall)
{
    long i = (long)blockIdx.x * 256 + threadIdx.x;
    if (i >= (long)NCOL * FAN / 4) return;
    long e = i * 4;
    int  g = (int)(e >> 19);
    long rem = e & 524287L;
    const float* src = (g == 0) ? Wf : (g == 1) ? Wi : (g == 2) ? Wo : Wj;
    float4 v = *(const float4*)(src + rem);
    us4 p = { f2b(v.x), f2b(v.y), f2b(v.z), f2b(v.w) };
    *(us4*)(Wall + e) = p;
}

// ---------------- kernel 0c: pack bias = [bf;bi;bo;bj] as f32 [2048] ----------------
__global__ void pack_bias(const float* __restrict__ bf_, const float* __restrict__ bi_,
                          const float* __restrict__ bo_, const float* __restrict__ bj_,
                          float* __restrict__ biasAll)
{
    int idx = blockIdx.x * 256 + threadIdx.x;
    if (idx >= NCOL) return;
    int g = idx >> 9;
    const float* s = (g == 0) ? bf_ : (g == 1) ? bi_ : (g == 2) ? bo_ : bj_;
    biasAll[idx] = s[idx & 511];
}

// ---------------- kernel 1: persistent-lite 256^2 8-phase GEMM (32x32x16) + bias -------
// Same staging pipeline / LDS layout / swizzle / vmcnt schedule as round 6/9 (verified).
// MFMA 32x32x16 swapped-operand: D col=lane&31 -> M-row, reg (r&3)+8(r>>2)+4(lane>>5)
// -> N-col. Epilogue mf-OUTER (each row's 128B line completed by 8 consecutive us4
// stores -- round-8-verified clean WRITE), bias in registers per tile.
__global__ __launch_bounds__(512)
void gemm_gates(const u16* __restrict__ A, const u16* __restrict__ W,
                const float* __restrict__ biasAll, u16* __restrict__ Cg)
{
    __shared__ u16 lds[2][4][8192];

    const int tid  = threadIdx.x;
    const int lane = tid & 63;
    const int wid  = tid >> 6;
    const int wm   = wid >> 2;         // 0..1
    const int wn   = wid & 3;          // 0..3

    // XCD-aware bijective swizzle (nwg = mtiles*2, always a multiple of 8)
    const int nwg = gridDim.x;
    const int swz = (blockIdx.x & 7) * (nwg >> 3) + (blockIdx.x >> 3);
    const long bm  = swz >> 1;
    const int  bn4 = (swz & 1) * TILES_PER_BLK;     // first N-tile: 0 or 4
    const long arow0 = bm * BM;

    const int sr = tid >> 3;           // staging row within half (i adds 64)
    const int ss = tid & 7;            // linear 16B slot

    facc16 acc[4][2];
#pragma unroll
    for (int i = 0; i < 4; ++i)
#pragma unroll
        for (int j = 0; j < 2; ++j)
#pragma unroll
            for (int e = 0; e < 16; ++e) acc[i][j][e] = 0.f;

    auto stageHalf = [&](int buf, int half, int ktg) {
        if (ktg >= TILES_PER_BLK * KTILES) ktg = 0;           // dummy: valid addr, never read
        const long k0    = (long)(ktg & (KTILES - 1)) * BK;
        const long bcol0 = ((long)bn4 + (ktg >> 4)) * BN;     // N-tile for this K-chunk
#pragma unroll
        for (int i = 0; i < 2; ++i) {
            const int r  = sr + i * 64;
            const int sx = ss ^ (r & 7);                      // inverse swizzle on source
            const u16* src = (half < 2)
                ? (A + (arow0 + half * 128 + r) * (long)FAN + k0 + sx * 8)
                : (W + (bcol0 + (half - 2) * 128 + r) * (long)FAN + k0 + sx * 8);
            gload16(src, &lds[buf][half][i * 4096 + wid * 512]);
        }
    };

    // prologue: K-tile 0 (all 4 halves) -> buf0; K-tile 1 B-halves -> buf1.
    stageHalf(0, 0, 0); stageHalf(0, 1, 0); stageHalf(0, 2, 0); stageHalf(0, 3, 0);
    stageHalf(1, 2, 1); stageHalf(1, 3, 1);
    asm volatile("s_waitcnt vmcnt(4)" ::: "memory");
    __builtin_amdgcn_s_barrier();

    const u16* Ah[2] = { &lds[0][wm][0],            &lds[1][wm][0] };
    const u16* Bh[2] = { &lds[0][2 + (wn >> 1)][0], &lds[1][2 + (wn >> 1)][0] };
    const int lrB0 = (wn & 1) * 64;
    const int l31  = lane & 31;
    const int h32  = lane >> 5;        // 0..1

#pragma unroll 1
    for (int tile = 0; tile < TILES_PER_BLK; ++tile) {
        const int kb = tile * KTILES;
#pragma unroll 1
        for (int t = 0; t < NITER; ++t) {
            bfrag bq[2][4];
#pragma unroll
            for (int p = 0; p < 8; ++p) {
                const int q  = p & 3;                         // M-frag (32 rows) this phase
                const int lt = p >> 2;
                bfrag aq[4];
                if (q == 0) {                                 // B-frags once per K-tile
#pragma unroll
                    for (int nf = 0; nf < 2; ++nf)
#pragma unroll
                        for (int ks = 0; ks < 4; ++ks) {
                            const int lr = lrB0 + nf * 32 + l31;
                            const int sl = (ks * 2 + h32) ^ (lr & 7);
                            bq[nf][ks] = *(const bfrag*)(Bh[lt] + lr * 64 + sl * 8);
                        }
                }
#pragma unroll
                for (int ks = 0; ks < 4; ++ks) {
                    const int lr = q * 32 + l31;
                    const int sl = (ks * 2 + h32) ^ (lr & 7);
                    aq[ks] = *(const bfrag*)(Ah[lt] + lr * 64 + sl * 8);
                }
                // continuous staging schedule (uniform; dummies clamp past the end)
                if (p == 0)      stageHalf(1, 0, kb + 2 * t + 1);
                else if (p == 1) stageHalf(1, 1, kb + 2 * t + 1);
                else if (p == 2) stageHalf(0, 2, kb + 2 * t + 2);
                else if (p == 3) stageHalf(0, 3, kb + 2 * t + 2);
                else if (p == 4) stageHalf(0, 0, kb + 2 * t + 2);
                else if (p == 5) stageHalf(0, 1, kb + 2 * t + 2);
                else if (p == 6) stageHalf(1, 2, kb + 2 * t + 3);
                else             stageHalf(1, 3, kb + 2 * t + 3);

                if (q == 0) asm volatile("s_waitcnt lgkmcnt(8)" ::: "memory");
                __builtin_amdgcn_s_barrier();
                asm volatile("s_waitcnt lgkmcnt(0)" ::: "memory");
                __builtin_amdgcn_s_setprio(1);
#pragma unroll
                for (int nf = 0; nf < 2; ++nf)
#pragma unroll
                    for (int ks = 0; ks < 4; ++ks)
                        // OPERAND-SWAPPED: D[i=N][j=M]
                        acc[q][nf] = __builtin_amdgcn_mfma_f32_32x32x16_bf16(
                            bq[nf][ks], aq[ks], acc[q][nf], 0, 0, 0);
                __builtin_amdgcn_s_setprio(0);
                if (q == 3) asm volatile("s_waitcnt vmcnt(4)" ::: "memory");  // counted, never 0
                __builtin_amdgcn_s_barrier();
            }
        }

        // epilogue for this tile: bias held in regs; mf-OUTER so each row's 128B
        // line (this wave's 64-col slice) is completed by 8 consecutive us4 stores.
        const long bcol0 = ((long)bn4 + tile) * BN;
        float4 bias4[2][4];
#pragma unroll
        for (int nf = 0; nf < 2; ++nf)
#pragma unroll
            for (int g = 0; g < 4; ++g)
                bias4[nf][g] = *(const float4*)(biasAll + bcol0 + wn * 64 + nf * 32
                                                + g * 8 + (h32 << 2));
#pragma unroll
        for (int mf = 0; mf < 4; ++mf) {
            const long m = arow0 + wm * 128 + mf * 32 + l31;
            u16* rowp = Cg + m * (long)NCOL;
#pragma unroll
            for (int nf = 0; nf < 2; ++nf)
#pragma unroll
                for (int g = 0; g < 4; ++g) {
                    const long n = bcol0 + wn * 64 + nf * 32 + g * 8 + (h32 << 2);
                    us4 pk = { f2b(acc[mf][nf][4 * g + 0] + bias4[nf][g].x),
                               f2b(acc[mf][nf][4 * g + 1] + bias4[nf][g].y),
                               f2b(acc[mf][nf][4 * g + 2] + bias4[nf][g].z),
                               f2b(acc[mf][nf][4 * g + 3] + bias4[nf][g].w) };
                    *(us4*)(rowp + n) = pk;
                }
        }
#pragma unroll
        for (int i = 0; i < 4; ++i)
#pragma unroll
            for (int j = 0; j < 2; ++j)
#pragma unroll
                for (int e = 0; e < 16; ++e) acc[i][j][e] = 0.f;
    }
}

// ---------------- kernel 2: grid-stride LN + activations, params register-resident ----
__global__ __launch_bounds__(256)
void lstm_act(const u16* __restrict__ pre, const float* __restrict__ pc,
              const float* __restrict__ gf, const float* __restrict__ btf,
              const float* __restrict__ gi, const float* __restrict__ bti,
              const float* __restrict__ go, const float* __restrict__ bto,
              const float* __restrict__ gj, const float* __restrict__ btj,
              const float* __restrict__ gc, const float* __restrict__ btc,
              float* __restrict__ out_h, float* __restrict__ out_c, long rows)
{
    const int  lane = threadIdx.x & 63;
    const int  c0   = lane * 8;
    const long wave = (long)blockIdx.x * 4 + (threadIdx.x >> 6);
    const long totW = (long)gridDim.x * 4;

    const float* gs[4]  = { gf, gi, go, gj };
    const float* bts[4] = { btf, bti, bto, btj };
    float gg[4][8], tt[4][8], gcv[8], tcv[8];
#pragma unroll
    for (int g = 0; g < 4; ++g) {
        *(float4*)&gg[g][0] = *(const float4*)(gs[g] + c0);
        *(float4*)&gg[g][4] = *(const float4*)(gs[g] + c0 + 4);
        *(float4*)&tt[g][0] = *(const float4*)(bts[g] + c0);
        *(float4*)&tt[g][4] = *(const float4*)(bts[g] + c0 + 4);
    }
    *(float4*)&gcv[0] = *(const float4*)(gc + c0);
    *(float4*)&gcv[4] = *(const float4*)(gc + c0 + 4);
    *(float4*)&tcv[0] = *(const float4*)(btc + c0);
    *(float4*)&tcv[4] = *(const float4*)(btc + c0 + 4);

#pragma unroll 1
    for (long row = wave; row < rows; row += totW) {
        float a4[4][8];
#pragma unroll
        for (int g = 0; g < 4; ++g) {
            us8 pv = *(const us8*)(pre + row * NCOL + g * HDIM + c0);
            float y[8];
            float s = 0.f, ssum = 0.f;
#pragma unroll
            for (int e = 0; e < 8; ++e) {
                y[e] = b2f(pv[e]);                 // bias already added in GEMM
                s += y[e]; ssum += y[e] * y[e];
            }
            float mean, rstd;
            wave_meanrstd(s, ssum, mean, rstd);
#pragma unroll
            for (int e = 0; e < 8; ++e) {
                float z = (y[e] - mean) * rstd * gg[g][e] + tt[g][e];
                a4[g][e] = (g == 3) ? fast_tanh(z) : fast_sigmoid(z);
            }
        }

        float4 p0 = *(const float4*)(pc + row * HDIM + c0);
        float4 p1 = *(const float4*)(pc + row * HDIM + c0 + 4);
        float pcv[8] = { p0.x, p0.y, p0.z, p0.w, p1.x, p1.y, p1.z, p1.w };
        float cr[8];
        float s = 0.f, ssum = 0.f;
#pragma unroll
        for (int e = 0; e < 8; ++e) {
            cr[e] = a4[0][e] * pcv[e] + fminf(1.f - a4[0][e], a4[1][e]) * a4[3][e];
            s += cr[e]; ssum += cr[e] * cr[e];
        }
        float mean, rstd;
        wave_meanrstd(s, ssum, mean, rstd);
        float hv[8], cv[8];
#pragma unroll
        for (int e = 0; e < 8; ++e) {
            float cc = (cr[e] - mean) * rstd * gcv[e] + tcv[e];
            cv[e] = cc;
            hv[e] = a4[2][e] * cc;
        }
        f4v h0 = { hv[0], hv[1], hv[2], hv[3] };
        f4v h1 = { hv[4], hv[5], hv[6], hv[7] };
        f4v c0v = { cv[0], cv[1], cv[2], cv[3] };
        f4v c1v = { cv[4], cv[5], cv[6], cv[7] };
        __builtin_nontemporal_store(h0,  (f4v*)(out_h + row * HDIM + c0));
        __builtin_nontemporal_store(h1,  (f4v*)(out_h + row * HDIM + c0 + 4));
        __builtin_nontemporal_store(c0v, (f4v*)(out_c + row * HDIM + c0));
        __builtin_nontemporal_store(c1v, (f4v*)(out_c + row * HDIM + c0 + 4));
    }
}

// ---------------- fallback (only if ws too small): fp32 naive, no workspace ----------------
static __device__ __forceinline__ void ln_pair(
    float y0, float y1,
    const float* __restrict__ gam, const float* __restrict__ bet, int c0,
    float* red, int lane, int wid, float& o0, float& o1)
{
    float s = y0 + y1, ss = y0 * y0 + y1 * y1;
#pragma unroll
    for (int o = 32; o; o >>= 1) { s += __shfl_down(s, o); ss += __shfl_down(ss, o); }
    if (lane == 0) { red[wid * 2] = s; red[wid * 2 + 1] = ss; }
    __syncthreads();
    float S  = red[0] + red[2] + red[4] + red[6];
    float SS = red[1] + red[3] + red[5] + red[7];
    __syncthreads();
    float mean = S * (1.f / 512.f);
    float var  = (SS - 512.f * mean * mean) * (1.f / 511.f);
    float rstd = 1.f / (sqrtf(fmaxf(var, 0.f)) + EPS);
    o0 = (y0 - mean) * rstd * gam[c0]     + bet[c0];
    o1 = (y1 - mean) * rstd * gam[c0 + 1] + bet[c0 + 1];
}

__global__ __launch_bounds__(256)
void lstm_naive(const float* __restrict__ x, const float* __restrict__ ph, const float* __restrict__ pc,
                const float* __restrict__ Wf, const float* __restrict__ bf_,
                const float* __restrict__ Wi, const float* __restrict__ bi_,
                const float* __restrict__ Wo, const float* __restrict__ bo_,
                const float* __restrict__ Wj, const float* __restrict__ bj_,
                const float* __restrict__ gf, const float* __restrict__ btf,
                const float* __restrict__ gi, const float* __restrict__ bti,
                const float* __restrict__ go, const float* __restrict__ bto,
                const float* __restrict__ gj, const float* __restrict__ btj,
                const float* __restrict__ gc, const float* __restrict__ btc,
                float* __restrict__ out_h, float* __restrict__ out_c)
{
    __shared__ float comb[FAN];
    __shared__ float red[8];
    const int b = blockIdx.x, t = threadIdx.x;
    const int lane = t & 63, wid = t >> 6;
    for (int k = t; k < D_IN; k += 256) {
        comb[k]        = x[(long)b * D_IN + k];
        comb[D_IN + k] = ph[(long)b * HDIM + k];
    }
    __syncthreads();
    const int c0 = t * 2;
    const float* Ws[4]  = { Wf, Wi, Wo, Wj };
    const float* bs[4]  = { bf_, bi_, bo_, bj_ };
    const float* gs[4]  = { gf, gi, go, gj };
    const float* bts[4] = { btf, bti, bto, btj };
    float a[4][2];
#pragma unroll
    for (int g = 0; g < 4; ++g) {
        float y[2];
#pragma unroll
        for (int e = 0; e < 2; ++e) {
            const float4* w4 = (const float4*)(Ws[g] + (long)(c0 + e) * FAN);
            const float4* c4 = (const float4*)comb;
            float s = 0.f;
            for (int k = 0; k < FAN / 4; ++k) {
                float4 wv = w4[k], cv = c4[k];
                s += wv.x * cv.x + wv.y * cv.y + wv.z * cv.z + wv.w * cv.w;
            }
            y[e] = s + bs[g][c0 + e];
        }
        ln_pair(y[0], y[1], gs[g], bts[g], c0, red, lane, wid, a[g][0], a[g][1]);
        if (g == 3) { a[g][0] = tanhf(a[g][0]); a[g][1] = tanhf(a[g][1]); }
        else        { a[g][0] = 1.f / (1.f + expf(-a[g][0]));
                      a[g][1] = 1.f / (1.f + expf(-a[g][1])); }
    }
    float2 pcv = *(const float2*)(pc + (long)b * HDIM + c0);
    float f0 = a[0][0], i0 = a[1][0], o0 = a[2][0], j0 = a[3][0];
    float f1 = a[0][1], i1 = a[1][1], o1 = a[2][1], j1 = a[3][1];
    float cr0 = f0 * pcv.x + fminf(1.f - f0, i0) * j0;
    float cr1 = f1 * pcv.y + fminf(1.f - f1, i1) * j1;
    float cc0, cc1;
    ln_pair(cr0, cr1, gc, btc, c0, red, lane, wid, cc0, cc1);
    *(float2*)(out_h + (long)b * HDIM + c0) = make_float2(o0 * cc0, o1 * cc1);
    *(float2*)(out_c + (long)b * HDIM + c0) = make_float2(cc0, cc1);
}

// ---------------- launcher ----------------
extern "C" void kernel_launch(void* const* d_in, const int* in_sizes, int n_in,
                              void* d_out, int out_size, void* d_ws, size_t ws_size,
                              hipStream_t stream)
{
    const float* x   = (const float*)d_in[0];
    const float* ph  = (const float*)d_in[1];
    const float* pc  = (const float*)d_in[2];
    const float* Wf  = (const float*)d_in[3];
    const float* bf_ = (const float*)d_in[4];
    const float* Wi  = (const float*)d_in[5];
    const float* bi_ = (const float*)d_in[6];
    const float* Wo  = (const float*)d_in[7];
    const float* bo_ = (const float*)d_in[8];
    const float* Wj  = (const float*)d_in[9];
    const float* bj_ = (const float*)d_in[10];
    const float* gf  = (const float*)d_in[11];
    const float* btf = (const float*)d_in[12];
    const float* gi  = (const float*)d_in[13];
    const float* bti = (const float*)d_in[14];
    const float* go  = (const float*)d_in[15];
    const float* bto = (const float*)d_in[16];
    const float* gj  = (const float*)d_in[17];
    const float* btj = (const float*)d_in[18];
    const float* gc  = (const float*)d_in[19];
    const float* btc = (const float*)d_in[20];
    float* out_h = (float*)d_out;
    float* out_c = out_h + (size_t)B_ROWS * HDIM;

    const size_t combElems  = (size_t)B_ROWS * FAN;            // bf16
    const size_t wElems     = (size_t)NCOL * FAN;              // bf16
    const size_t biasBytes  = (size_t)NCOL * sizeof(float);    // 8 KB
    const size_t fixedBytes = (combElems + wElems) * 2 + biasBytes;

    long slabRows = 0;
    if (ws_size > fixedBytes) {
        size_t avail = ws_size - fixedBytes;
        slabRows = (long)(avail / ((size_t)NCOL * 2));
        slabRows &= ~1023L;                                 // grid = (rows/256)*2 must be %8
        if (slabRows > B_ROWS) slabRows = B_ROWS;
    }

    if (slabRows >= 1024) {
        u16*   comb    = (u16*)d_ws;
        u16*   Wall    = comb + combElems;
        float* biasAll = (float*)(Wall + wElems);
        u16*   pre     = (u16*)(biasAll + NCOL);
        pack_combined<<<dim3((unsigned)((B_ROWS * (long)D_IN / 4 + 255) / 256)), dim3(256), 0, stream>>>(x, ph, comb);
        pack_w<<<dim3((unsigned)(((long)NCOL * FAN / 4 + 255) / 256)), dim3(256), 0, stream>>>(Wf, Wi, Wo, Wj, Wall);
        pack_bias<<<dim3(8), dim3(256), 0, stream>>>(bf_, bi_, bo_, bj_, biasAll);
        for (long r0 = 0; r0 < B_ROWS; r0 += slabRows) {
            long rows = B_ROWS - r0; if (rows > slabRows) rows = slabRows;
            const unsigned nwg = (unsigned)((rows / BM) * 2);   // 2 blocks per M-tile (4 N-tiles each)
            gemm_gates<<<dim3(nwg), dim3(512), 0, stream>>>(comb + r0 * FAN, Wall, biasAll, pre);
            lstm_act<<<dim3(2048), dim3(256), 0, stream>>>(
                pre, pc + r0 * HDIM,
                gf, btf, gi, bti, go, bto, gj, btj, gc, btc,
                out_h + r0 * HDIM, out_c + r0 * HDIM, rows);
        }
    } else {
        lstm_naive<<<dim3(B_ROWS), dim3(256), 0, stream>>>(
            x, ph, pc, Wf, bf_, Wi, bi_, Wo, bo_, Wj, bj_,
            gf, btf, gi, bti, go, bto, gj, btj, gc, btc, out_h, out_c);
    }
}

// Round 12
// 515.114 us; speedup vs baseline: 1.0935x; 1.0858x over previous
//
#include <hip/hip_runtime.h>
#include <math.h>

// ---------------- problem constants ----------------
#define B_ROWS 65536
#define D_IN   512
#define HDIM   512
#define FAN    1024          // D_IN + HDIM
#define NCOL   2048          // 4 gates * HDIM
#define EPS    1e-5f

// GEMM tile (256^2 8-phase, persistent-lite: 4 N-tiles per block), 16x16x32 MFMA
#define BM 256
#define BN 256
#define BK 64
#define KTILES (FAN / BK)    // 16 per output tile
#define NITER  (KTILES / 2)  // 8 iterations, 2 K-tiles each
#define TILES_PER_BLK 4      // N-tiles per block (half of NCOL/BN)

typedef unsigned short u16;
using bfrag = __attribute__((ext_vector_type(8))) short;          // 8 bf16 (4 VGPRs)
using facc  = __attribute__((ext_vector_type(4))) float;          // 4 fp32 acc
using us4   = __attribute__((ext_vector_type(4))) unsigned short;
using us8   = __attribute__((ext_vector_type(8))) unsigned short;
using f4v   = __attribute__((ext_vector_type(4))) float;          // clang vec for nontemporal

// ---------------- helpers ----------------
static __device__ __forceinline__ u16 f2b(float f) {              // fp32 -> bf16 RNE
    unsigned u = __builtin_bit_cast(unsigned, f);
    u += 0x7fffu + ((u >> 16) & 1u);
    return (u16)(u >> 16);
}
static __device__ __forceinline__ float b2f(u16 h) {
    unsigned u = ((unsigned)h) << 16;
    return __builtin_bit_cast(float, u);
}
static __device__ __forceinline__ void gload16(const u16* g, u16* l) {
    __builtin_amdgcn_global_load_lds(
        (const __attribute__((address_space(1))) void*)g,
        (__attribute__((address_space(3))) void*)l, 16, 0, 0);
}
static __device__ __forceinline__ void wave_meanrstd(float s, float ss, float& mean, float& rstd)
{
#pragma unroll
    for (int o = 1; o < 64; o <<= 1) { s += __shfl_xor(s, o); ss += __shfl_xor(ss, o); }
    mean = s * (1.f / 512.f);
    float var = (ss - 512.f * mean * mean) * (1.f / 511.f);
    rstd = 1.f / (sqrtf(fmaxf(var, 0.f)) + EPS);
}
static __device__ __forceinline__ float fast_sigmoid(float z) {
    return __fdividef(1.f, 1.f + __expf(-z));
}
static __device__ __forceinline__ float fast_tanh(float z) {
    return __fdividef(2.f, 1.f + __expf(-2.f * z)) - 1.f;
}

// ---------------- kernel 0a: pack combined = concat(x, prev_h) as bf16 ----------------
__global__ void pack_combined(const float* __restrict__ x, const float* __restrict__ ph,
                              u16* __restrict__ comb)
{
    long i = (long)blockIdx.x * 256 + threadIdx.x;
    if (i >= (long)B_ROWS * D_IN / 4) return;
    long e = i * 4;
    long b = e >> 9;
    int  d = (int)(e & 511);
    float4 xv = *(const float4*)(x + e);
    float4 hv = *(const float4*)(ph + e);
    us4 xb = { f2b(xv.x), f2b(xv.y), f2b(xv.z), f2b(xv.w) };
    us4 hb = { f2b(hv.x), f2b(hv.y), f2b(hv.z), f2b(hv.w) };
    *(us4*)(comb + b * FAN + d)        = xb;
    *(us4*)(comb + b * FAN + D_IN + d) = hb;
}

// ---------------- kernel 0b: pack W = [Wf;Wi;Wo;Wj] as bf16 [2048][1024] ----------------
__global__ void pack_w(const float* __restrict__ Wf, const float* __restrict__ Wi,
                       const float* __restrict__ Wo, const float* __restrict__ Wj,
                       u16* __restrict__ Wall)
{
    long i = (long)blockIdx.x * 256 + threadIdx.x;
    if (i >= (long)NCOL * FAN / 4) return;
    long e = i * 4;
    int  g = (int)(e >> 19);
    long rem = e & 524287L;
    const float* src = (g == 0) ? Wf : (g == 1) ? Wi : (g == 2) ? Wo : Wj;
    float4 v = *(const float4*)(src + rem);
    us4 p = { f2b(v.x), f2b(v.y), f2b(v.z), f2b(v.w) };
    *(us4*)(Wall + e) = p;
}

// ---------------- kernel 0c: pack bias = [bf;bi;bo;bj] as f32 [2048] ----------------
__global__ void pack_bias(const float* __restrict__ bf_, const float* __restrict__ bi_,
                          const float* __restrict__ bo_, const float* __restrict__ bj_,
                          float* __restrict__ biasAll)
{
    int idx = blockIdx.x * 256 + threadIdx.x;
    if (idx >= NCOL) return;
    int g = idx >> 9;
    const float* s = (g == 0) ? bf_ : (g == 1) ? bi_ : (g == 2) ? bo_ : bj_;
    biasAll[idx] = s[idx & 511];
}

// ---------------- kernel 1: persistent-lite 256^2 8-phase GEMM (16x16x32) + bias -------
// Round-9 kernel with ONE change: epilogue is mf-OUTER / nf-INNER (round-8-verified
// clean WRITE ~262 MB) instead of nf-outer (round-9: +90 MB partial-line writebacks).
// Swapped-operand MFMA 16x16x32 (round-8-verified conflict-free reads, packed stores):
// D col=lane&15 -> M-row, regs -> 4 consecutive N-cols.
__global__ __launch_bounds__(512)
void gemm_gates(const u16* __restrict__ A, const u16* __restrict__ W,
                const float* __restrict__ biasAll, u16* __restrict__ Cg)
{
    __shared__ u16 lds[2][4][8192];

    const int tid  = threadIdx.x;
    const int lane = tid & 63;
    const int wid  = tid >> 6;
    const int wm   = wid >> 2;         // 0..1
    const int wn   = wid & 3;          // 0..3

    // XCD-aware bijective swizzle (nwg = mtiles*2, always a multiple of 8)
    const int nwg = gridDim.x;
    const int swz = (blockIdx.x & 7) * (nwg >> 3) + (blockIdx.x >> 3);
    const long bm  = swz >> 1;
    const int  bn4 = (swz & 1) * TILES_PER_BLK;     // first N-tile: 0 or 4
    const long arow0 = bm * BM;

    const int sr = tid >> 3;           // staging row within half (i adds 64)
    const int ss = tid & 7;            // linear 16B slot

    facc acc[8][4];
#pragma unroll
    for (int i = 0; i < 8; ++i)
#pragma unroll
        for (int j = 0; j < 4; ++j) acc[i][j] = facc{0.f, 0.f, 0.f, 0.f};

    auto stageHalf = [&](int buf, int half, int ktg) {
        if (ktg >= TILES_PER_BLK * KTILES) ktg = 0;           // dummy: valid addr, never read
        const long k0    = (long)(ktg & (KTILES - 1)) * BK;
        const long bcol0 = ((long)bn4 + (ktg >> 4)) * BN;     // N-tile for this K-chunk
#pragma unroll
        for (int i = 0; i < 2; ++i) {
            const int r  = sr + i * 64;
            const int sx = ss ^ (r & 7);                      // inverse swizzle on source
            const u16* src = (half < 2)
                ? (A + (arow0 + half * 128 + r) * (long)FAN + k0 + sx * 8)
                : (W + (bcol0 + (half - 2) * 128 + r) * (long)FAN + k0 + sx * 8);
            gload16(src, &lds[buf][half][i * 4096 + wid * 512]);
        }
    };

    // prologue: K-tile 0 (all 4 halves) -> buf0; K-tile 1 B-halves -> buf1.
    stageHalf(0, 0, 0); stageHalf(0, 1, 0); stageHalf(0, 2, 0); stageHalf(0, 3, 0);
    stageHalf(1, 2, 1); stageHalf(1, 3, 1);
    asm volatile("s_waitcnt vmcnt(4)" ::: "memory");
    __builtin_amdgcn_s_barrier();

    const u16* Ah[2] = { &lds[0][wm][0],            &lds[1][wm][0] };
    const u16* Bh[2] = { &lds[0][2 + (wn >> 1)][0], &lds[1][2 + (wn >> 1)][0] };
    const int lrB0 = (wn & 1) * 64;

#pragma unroll 1
    for (int tile = 0; tile < TILES_PER_BLK; ++tile) {
        const int kb = tile * KTILES;
#pragma unroll 1
        for (int t = 0; t < NITER; ++t) {
            bfrag bq[4][2];
#pragma unroll
            for (int p = 0; p < 8; ++p) {
                const int q  = p & 3;
                const int lt = p >> 2;
                bfrag aq[2][2];
                if (q == 0) {                                 // B-frags once per K-tile
#pragma unroll
                    for (int nf = 0; nf < 4; ++nf)
#pragma unroll
                        for (int kk = 0; kk < 2; ++kk) {
                            const int lr = lrB0 + nf * 16 + (lane & 15);
                            const int sl = (kk * 4 + (lane >> 4)) ^ (lane & 7);
                            bq[nf][kk] = *(const bfrag*)(Bh[lt] + lr * 64 + sl * 8);
                        }
                }
#pragma unroll
                for (int m2 = 0; m2 < 2; ++m2)                // A quadrant (2 M-frags)
#pragma unroll
                    for (int kk = 0; kk < 2; ++kk) {
                        const int lr = (q * 2 + m2) * 16 + (lane & 15);
                        const int sl = (kk * 4 + (lane >> 4)) ^ (lane & 7);
                        aq[m2][kk] = *(const bfrag*)(Ah[lt] + lr * 64 + sl * 8);
                    }
                // continuous staging schedule (uniform; dummies clamp past the end)
                if (p == 0)      stageHalf(1, 0, kb + 2 * t + 1);
                else if (p == 1) stageHalf(1, 1, kb + 2 * t + 1);
                else if (p == 2) stageHalf(0, 2, kb + 2 * t + 2);
                else if (p == 3) stageHalf(0, 3, kb + 2 * t + 2);
                else if (p == 4) stageHalf(0, 0, kb + 2 * t + 2);
                else if (p == 5) stageHalf(0, 1, kb + 2 * t + 2);
                else if (p == 6) stageHalf(1, 2, kb + 2 * t + 3);
                else             stageHalf(1, 3, kb + 2 * t + 3);

                if (q == 0) asm volatile("s_waitcnt lgkmcnt(8)" ::: "memory");
                __builtin_amdgcn_s_barrier();
                asm volatile("s_waitcnt lgkmcnt(0)" ::: "memory");
                __builtin_amdgcn_s_setprio(1);
#pragma unroll
                for (int m2 = 0; m2 < 2; ++m2)
#pragma unroll
                    for (int nf = 0; nf < 4; ++nf)
#pragma unroll
                        for (int kk = 0; kk < 2; ++kk)
                            // OPERAND-SWAPPED: D[i=N][j=M]; regs -> 4 consecutive N-cols
                            acc[q * 2 + m2][nf] = __builtin_amdgcn_mfma_f32_16x16x32_bf16(
                                bq[nf][kk], aq[m2][kk], acc[q * 2 + m2][nf], 0, 0, 0);
                __builtin_amdgcn_s_setprio(0);
                if (q == 3) asm volatile("s_waitcnt vmcnt(4)" ::: "memory");  // counted, never 0
                __builtin_amdgcn_s_barrier();
            }
        }

        // epilogue: mf-OUTER / nf-INNER (round-8 ordering, WRITE clean). Per row m,
        // this wave's 4 consecutive us4 stores complete its 128B slice before moving
        // to the next row. Bias held in registers (4 float4).
        const long bcol0 = ((long)bn4 + tile) * BN;
        float4 bias4[4];
#pragma unroll
        for (int nf = 0; nf < 4; ++nf)
            bias4[nf] = *(const float4*)(biasAll + bcol0 + wn * 64 + nf * 16
                                         + ((lane >> 4) << 2));
#pragma unroll
        for (int mf = 0; mf < 8; ++mf) {
            const long m = arow0 + wm * 128 + mf * 16 + (lane & 15);
            u16* rowp = Cg + m * (long)NCOL;
#pragma unroll
            for (int nf = 0; nf < 4; ++nf) {
                const long n = bcol0 + wn * 64 + nf * 16 + ((lane >> 4) << 2);
                us4 pk = { f2b(acc[mf][nf][0] + bias4[nf].x),
                           f2b(acc[mf][nf][1] + bias4[nf].y),
                           f2b(acc[mf][nf][2] + bias4[nf].z),
                           f2b(acc[mf][nf][3] + bias4[nf].w) };
                *(us4*)(rowp + n) = pk;
                acc[mf][nf] = facc{0.f, 0.f, 0.f, 0.f};
            }
        }
    }
}

// ---------------- kernel 2: grid-stride LN + activations, params register-resident ----
__global__ __launch_bounds__(256)
void lstm_act(const u16* __restrict__ pre, const float* __restrict__ pc,
              const float* __restrict__ gf, const float* __restrict__ btf,
              const float* __restrict__ gi, const float* __restrict__ bti,
              const float* __restrict__ go, const float* __restrict__ bto,
              const float* __restrict__ gj, const float* __restrict__ btj,
              const float* __restrict__ gc, const float* __restrict__ btc,
              float* __restrict__ out_h, float* __restrict__ out_c, long rows)
{
    const int  lane = threadIdx.x & 63;
    const int  c0   = lane * 8;
    const long wave = (long)blockIdx.x * 4 + (threadIdx.x >> 6);
    const long totW = (long)gridDim.x * 4;

    const float* gs[4]  = { gf, gi, go, gj };
    const float* bts[4] = { btf, bti, bto, btj };
    float gg[4][8], tt[4][8], gcv[8], tcv[8];
#pragma unroll
    for (int g = 0; g < 4; ++g) {
        *(float4*)&gg[g][0] = *(const float4*)(gs[g] + c0);
        *(float4*)&gg[g][4] = *(const float4*)(gs[g] + c0 + 4);
        *(float4*)&tt[g][0] = *(const float4*)(bts[g] + c0);
        *(float4*)&tt[g][4] = *(const float4*)(bts[g] + c0 + 4);
    }
    *(float4*)&gcv[0] = *(const float4*)(gc + c0);
    *(float4*)&gcv[4] = *(const float4*)(gc + c0 + 4);
    *(float4*)&tcv[0] = *(const float4*)(btc + c0);
    *(float4*)&tcv[4] = *(const float4*)(btc + c0 + 4);

#pragma unroll 1
    for (long row = wave; row < rows; row += totW) {
        float a4[4][8];
#pragma unroll
        for (int g = 0; g < 4; ++g) {
            us8 pv = *(const us8*)(pre + row * NCOL + g * HDIM + c0);
            float y[8];
            float s = 0.f, ssum = 0.f;
#pragma unroll
            for (int e = 0; e < 8; ++e) {
                y[e] = b2f(pv[e]);                 // bias already added in GEMM
                s += y[e]; ssum += y[e] * y[e];
            }
            float mean, rstd;
            wave_meanrstd(s, ssum, mean, rstd);
#pragma unroll
            for (int e = 0; e < 8; ++e) {
                float z = (y[e] - mean) * rstd * gg[g][e] + tt[g][e];
                a4[g][e] = (g == 3) ? fast_tanh(z) : fast_sigmoid(z);
            }
        }

        float4 p0 = *(const float4*)(pc + row * HDIM + c0);
        float4 p1 = *(const float4*)(pc + row * HDIM + c0 + 4);
        float pcv[8] = { p0.x, p0.y, p0.z, p0.w, p1.x, p1.y, p1.z, p1.w };
        float cr[8];
        float s = 0.f, ssum = 0.f;
#pragma unroll
        for (int e = 0; e < 8; ++e) {
            cr[e] = a4[0][e] * pcv[e] + fminf(1.f - a4[0][e], a4[1][e]) * a4[3][e];
            s += cr[e]; ssum += cr[e] * cr[e];
        }
        float mean, rstd;
        wave_meanrstd(s, ssum, mean, rstd);
        float hv[8], cv[8];
#pragma unroll
        for (int e = 0; e < 8; ++e) {
            float cc = (cr[e] - mean) * rstd * gcv[e] + tcv[e];
            cv[e] = cc;
            hv[e] = a4[2][e] * cc;
        }
        f4v h0 = { hv[0], hv[1], hv[2], hv[3] };
        f4v h1 = { hv[4], hv[5], hv[6], hv[7] };
        f4v c0v = { cv[0], cv[1], cv[2], cv[3] };
        f4v c1v = { cv[4], cv[5], cv[6], cv[7] };
        __builtin_nontemporal_store(h0,  (f4v*)(out_h + row * HDIM + c0));
        __builtin_nontemporal_store(h1,  (f4v*)(out_h + row * HDIM + c0 + 4));
        __builtin_nontemporal_store(c0v, (f4v*)(out_c + row * HDIM + c0));
        __builtin_nontemporal_store(c1v, (f4v*)(out_c + row * HDIM + c0 + 4));
    }
}

// ---------------- fallback (only if ws too small): fp32 naive, no workspace ----------------
static __device__ __forceinline__ void ln_pair(
    float y0, float y1,
    const float* __restrict__ gam, const float* __restrict__ bet, int c0,
    float* red, int lane, int wid, float& o0, float& o1)
{
    float s = y0 + y1, ss = y0 * y0 + y1 * y1;
#pragma unroll
    for (int o = 32; o; o >>= 1) { s += __shfl_down(s, o); ss += __shfl_down(ss, o); }
    if (lane == 0) { red[wid * 2] = s; red[wid * 2 + 1] = ss; }
    __syncthreads();
    float S  = red[0] + red[2] + red[4] + red[6];
    float SS = red[1] + red[3] + red[5] + red[7];
    __syncthreads();
    float mean = S * (1.f / 512.f);
    float var  = (SS - 512.f * mean * mean) * (1.f / 511.f);
    float rstd = 1.f / (sqrtf(fmaxf(var, 0.f)) + EPS);
    o0 = (y0 - mean) * rstd * gam[c0]     + bet[c0];
    o1 = (y1 - mean) * rstd * gam[c0 + 1] + bet[c0 + 1];
}

__global__ __launch_bounds__(256)
void lstm_naive(const float* __restrict__ x, const float* __restrict__ ph, const float* __restrict__ pc,
                const float* __restrict__ Wf, const float* __restrict__ bf_,
                const float* __restrict__ Wi, const float* __restrict__ bi_,
                const float* __restrict__ Wo, const float* __restrict__ bo_,
                const float* __restrict__ Wj, const float* __restrict__ bj_,
                const float* __restrict__ gf, const float* __restrict__ btf,
                const float* __restrict__ gi, const float* __restrict__ bti,
                const float* __restrict__ go, const float* __restrict__ bto,
                const float* __restrict__ gj, const float* __restrict__ btj,
                const float* __restrict__ gc, const float* __restrict__ btc,
                float* __restrict__ out_h, float* __restrict__ out_c)
{
    __shared__ float comb[FAN];
    __shared__ float red[8];
    const int b = blockIdx.x, t = threadIdx.x;
    const int lane = t & 63, wid = t >> 6;
    for (int k = t; k < D_IN; k += 256) {
        comb[k]        = x[(long)b * D_IN + k];
        comb[D_IN + k] = ph[(long)b * HDIM + k];
    }
    __syncthreads();
    const int c0 = t * 2;
    const float* Ws[4]  = { Wf, Wi, Wo, Wj };
    const float* bs[4]  = { bf_, bi_, bo_, bj_ };
    const float* gs[4]  = { gf, gi, go, gj };
    const float* bts[4] = { btf, bti, bto, btj };
    float a[4][2];
#pragma unroll
    for (int g = 0; g < 4; ++g) {
        float y[2];
#pragma unroll
        for (int e = 0; e < 2; ++e) {
            const float4* w4 = (const float4*)(Ws[g] + (long)(c0 + e) * FAN);
            const float4* c4 = (const float4*)comb;
            float s = 0.f;
            for (int k = 0; k < FAN / 4; ++k) {
                float4 wv = w4[k], cv = c4[k];
                s += wv.x * cv.x + wv.y * cv.y + wv.z * cv.z + wv.w * cv.w;
            }
            y[e] = s + bs[g][c0 + e];
        }
        ln_pair(y[0], y[1], gs[g], bts[g], c0, red, lane, wid, a[g][0], a[g][1]);
        if (g == 3) { a[g][0] = tanhf(a[g][0]); a[g][1] = tanhf(a[g][1]); }
        else        { a[g][0] = 1.f / (1.f + expf(-a[g][0]));
                      a[g][1] = 1.f / (1.f + expf(-a[g][1])); }
    }
    float2 pcv = *(const float2*)(pc + (long)b * HDIM + c0);
    float f0 = a[0][0], i0 = a[1][0], o0 = a[2][0], j0 = a[3][0];
    float f1 = a[0][1], i1 = a[1][1], o1 = a[2][1], j1 = a[3][1];
    float cr0 = f0 * pcv.x + fminf(1.f - f0, i0) * j0;
    float cr1 = f1 * pcv.y + fminf(1.f - f1, i1) * j1;
    float cc0, cc1;
    ln_pair(cr0, cr1, gc, btc, c0, red, lane, wid, cc0, cc1);
    *(float2*)(out_h + (long)b * HDIM + c0) = make_float2(o0 * cc0, o1 * cc1);
    *(float2*)(out_c + (long)b * HDIM + c0) = make_float2(cc0, cc1);
}

// ---------------- launcher ----------------
extern "C" void kernel_launch(void* const* d_in, const int* in_sizes, int n_in,
                              void* d_out, int out_size, void* d_ws, size_t ws_size,
                              hipStream_t stream)
{
    const float* x   = (const float*)d_in[0];
    const float* ph  = (const float*)d_in[1];
    const float* pc  = (const float*)d_in[2];
    const float* Wf  = (const float*)d_in[3];
    const float* bf_ = (const float*)d_in[4];
    const float* Wi  = (const float*)d_in[5];
    const float* bi_ = (const float*)d_in[6];
    const float* Wo  = (const float*)d_in[7];
    const float* bo_ = (const float*)d_in[8];
    const float* Wj  = (const float*)d_in[9];
    const float* bj_ = (const float*)d_in[10];
    const float* gf  = (const float*)d_in[11];
    const float* btf = (const float*)d_in[12];
    const float* gi  = (const float*)d_in[13];
    const float* bti = (const float*)d_in[14];
    const float* go  = (const float*)d_in[15];
    const float* bto = (const float*)d_in[16];
    const float* gj  = (const float*)d_in[17];
    const float* btj = (const float*)d_in[18];
    const float* gc  = (const float*)d_in[19];
    const float* btc = (const float*)d_in[20];
    float* out_h = (float*)d_out;
    float* out_c = out_h + (size_t)B_ROWS * HDIM;

    const size_t combElems  = (size_t)B_ROWS * FAN;            // bf16
    const size_t wElems     = (size_t)NCOL * FAN;              // bf16
    const size_t biasBytes  = (size_t)NCOL * sizeof(float);    // 8 KB
    const size_t fixedBytes = (combElems + wElems) * 2 + biasBytes;

    long slabRows = 0;
    if (ws_size > fixedBytes) {
        size_t avail = ws_size - fixedBytes;
        slabRows = (long)(avail / ((size_t)NCOL * 2));
        slabRows &= ~1023L;                                 // grid = (rows/256)*2 must be %8
        if (slabRows > B_ROWS) slabRows = B_ROWS;
    }

    if (slabRows >= 1024) {
        u16*   comb    = (u16*)d_ws;
        u16*   Wall    = comb + combElems;
        float* biasAll = (float*)(Wall + wElems);
        u16*   pre     = (u16*)(biasAll + NCOL);
        pack_combined<<<dim3((unsigned)((B_ROWS * (long)D_IN / 4 + 255) / 256)), dim3(256), 0, stream>>>(x, ph, comb);
        pack_w<<<dim3((unsigned)(((long)NCOL * FAN / 4 + 255) / 256)), dim3(256), 0, stream>>>(Wf, Wi, Wo, Wj, Wall);
        pack_bias<<<dim3(8), dim3(256), 0, stream>>>(bf_, bi_, bo_, bj_, biasAll);
        for (long r0 = 0; r0 < B_ROWS; r0 += slabRows) {
            long rows = B_ROWS - r0; if (rows > slabRows) rows = slabRows;
            const unsigned nwg = (unsigned)((rows / BM) * 2);   // 2 blocks per M-tile (4 N-tiles each)
            gemm_gates<<<dim3(nwg), dim3(512), 0, stream>>>(comb + r0 * FAN, Wall, biasAll, pre);
            lstm_act<<<dim3(2048), dim3(256), 0, stream>>>(
                pre, pc + r0 * HDIM,
                gf, btf, gi, bti, go, bto, gj, btj, gc, btc,
                out_h + r0 * HDIM, out_c + r0 * HDIM, rows);
        }
    } else {
        lstm_naive<<<dim3(B_ROWS), dim3(256), 0, stream>>>(
            x, ph, pc, Wf, bf_, Wi, bi_, Wo, bo_, Wj, bj_,
            gf, btf, gi, bti, go, bto, gj, btj, gc, btc, out_h, out_c);
    }
}

// Round 13
// 497.104 us; speedup vs baseline: 1.1332x; 1.0362x over previous
//
#include <hip/hip_runtime.h>
#include <math.h>

// ---------------- problem constants ----------------
#define B_ROWS 65536
#define D_IN   512
#define HDIM   512
#define FAN    1024          // D_IN + H
#define NCOL   2048          // 4 gates * HDIM
#define EPS    1e-5f

// GEMM tile (256^2 8-phase, persistent-lite: 4 N-tiles per block), 16x16x32 MFMA
#define BM 256
#define BN 256
#define BK 64
#define KTILES (FAN / BK)    // 16 per output tile
#define NITER  (KTILES / 2)  // 8 iterations, 2 K-tiles each
#define TILES_PER_BLK 4      // N-tiles per block (half of NCOL/BN)
#define SLAB_ROWS 32768L     // 2 slabs: pre-slab (128 MB) stays L3-resident for act

typedef unsigned short u16;
using bfrag = __attribute__((ext_vector_type(8))) short;          // 8 bf16 (4 VGPRs)
using facc  = __attribute__((ext_vector_type(4))) float;          // 4 fp32 acc
using us4   = __attribute__((ext_vector_type(4))) unsigned short;
using us8   = __attribute__((ext_vector_type(8))) unsigned short;
using f4v   = __attribute__((ext_vector_type(4))) float;          // clang vec for nontemporal

// ---------------- helpers ----------------
static __device__ __forceinline__ u16 f2b(float f) {              // fp32 -> bf16 RNE
    unsigned u = __builtin_bit_cast(unsigned, f);
    u += 0x7fffu + ((u >> 16) & 1u);
    return (u16)(u >> 16);
}
static __device__ __forceinline__ float b2f(u16 h) {
    unsigned u = ((unsigned)h) << 16;
    return __builtin_bit_cast(float, u);
}
static __device__ __forceinline__ void gload16(const u16* g, u16* l) {
    __builtin_amdgcn_global_load_lds(
        (const __attribute__((address_space(1))) void*)g,
        (__attribute__((address_space(3))) void*)l, 16, 0, 0);
}
static __device__ __forceinline__ void wave_meanrstd(float s, float ss, float& mean, float& rstd)
{
#pragma unroll
    for (int o = 1; o < 64; o <<= 1) { s += __shfl_xor(s, o); ss += __shfl_xor(ss, o); }
    mean = s * (1.f / 512.f);
    float var = (ss - 512.f * mean * mean) * (1.f / 511.f);
    rstd = 1.f / (sqrtf(fmaxf(var, 0.f)) + EPS);
}
static __device__ __forceinline__ float fast_sigmoid(float z) {
    return __fdividef(1.f, 1.f + __expf(-z));
}
static __device__ __forceinline__ float fast_tanh(float z) {
    return __fdividef(2.f, 1.f + __expf(-2.f * z)) - 1.f;
}

// ---------------- kernel 0a: pack combined = concat(x, prev_h) as bf16 ----------------
__global__ void pack_combined(const float* __restrict__ x, const float* __restrict__ ph,
                              u16* __restrict__ comb)
{
    long i = (long)blockIdx.x * 256 + threadIdx.x;
    if (i >= (long)B_ROWS * D_IN / 4) return;
    long e = i * 4;
    long b = e >> 9;
    int  d = (int)(e & 511);
    float4 xv = *(const float4*)(x + e);
    float4 hv = *(const float4*)(ph + e);
    us4 xb = { f2b(xv.x), f2b(xv.y), f2b(xv.z), f2b(xv.w) };
    us4 hb = { f2b(hv.x), f2b(hv.y), f2b(hv.z), f2b(hv.w) };
    *(us4*)(comb + b * FAN + d)        = xb;
    *(us4*)(comb + b * FAN + D_IN + d) = hb;
}

// ---------------- kernel 0b: pack W = [Wf;Wi;Wo;Wj] as bf16 [2048][1024] ----------------
__global__ void pack_w(const float* __restrict__ Wf, const float* __restrict__ Wi,
                       const float* __restrict__ Wo, const float* __restrict__ Wj,
                       u16* __restrict__ Wall)
{
    long i = (long)blockIdx.x * 256 + threadIdx.x;
    if (i >= (long)NCOL * FAN / 4) return;
    long e = i * 4;
    int  g = (int)(e >> 19);
    long rem = e & 524287L;
    const float* src = (g == 0) ? Wf : (g == 1) ? Wi : (g == 2) ? Wo : Wj;
    float4 v = *(const float4*)(src + rem);
    us4 p = { f2b(v.x), f2b(v.y), f2b(v.z), f2b(v.w) };
    *(us4*)(Wall + e) = p;
}

// ---------------- kernel 0c: pack bias = [bf;bi;bo;bj] as f32 [2048] ----------------
__global__ void pack_bias(const float* __restrict__ bf_, const float* __restrict__ bi_,
                          const float* __restrict__ bo_, const float* __restrict__ bj_,
                          float* __restrict__ biasAll)
{
    int idx = blockIdx.x * 256 + threadIdx.x;
    if (idx >= NCOL) return;
    int g = idx >> 9;
    const float* s = (g == 0) ? bf_ : (g == 1) ? bi_ : (g == 2) ? bo_ : bj_;
    biasAll[idx] = s[idx & 511];
}

// ---------------- kernel 1: persistent-lite 256^2 8-phase GEMM (round-6 core) ----------
// EXACT round-6 measured-best core (265 us): normal operand order mfma(A,B),
// continuous staging across 4 N-tiles, counted vmcnt(4), scalar-u16 epilogue
// (D: row=(lane>>4)*4+r -> M, col=lane&15 -> N; WRITE measured clean at 262 MB).
// Only delta vs round 6: bias (f32, per-lane scalar per nf) fused before f2b.
__global__ __launch_bounds__(512)
void gemm_gates(const u16* __restrict__ A, const u16* __restrict__ W,
                const float* __restrict__ biasAll, u16* __restrict__ Cg)
{
    __shared__ u16 lds[2][4][8192];

    const int tid  = threadIdx.x;
    const int lane = tid & 63;
    const int wid  = tid >> 6;
    const int wm   = wid >> 2;         // 0..1
    const int wn   = wid & 3;          // 0..3

    // XCD-aware bijective swizzle (nwg = mtiles*2, always a multiple of 8).
    // Consecutive swz pairs (same bm) land in the same XCD chunk -> panel L2 sharing.
    const int nwg = gridDim.x;
    const int swz = (blockIdx.x & 7) * (nwg >> 3) + (blockIdx.x >> 3);
    const long bm  = swz >> 1;
    const int  bn4 = (swz & 1) * TILES_PER_BLK;     // first N-tile: 0 or 4
    const long arow0 = bm * BM;

    const int sr = tid >> 3;           // staging row within half (i adds 64)
    const int ss = tid & 7;            // linear 16B slot

    facc acc[8][4];
#pragma unroll
    for (int i = 0; i < 8; ++i)
#pragma unroll
        for (int j = 0; j < 4; ++j) acc[i][j] = facc{0.f, 0.f, 0.f, 0.f};

    auto stageHalf = [&](int buf, int half, int ktg) {
        if (ktg >= TILES_PER_BLK * KTILES) ktg = 0;           // dummy: valid addr, never read
        const long k0    = (long)(ktg & (KTILES - 1)) * BK;
        const long bcol0 = ((long)bn4 + (ktg >> 4)) * BN;     // N-tile for this K-chunk
#pragma unroll
        for (int i = 0; i < 2; ++i) {
            const int r  = sr + i * 64;
            const int sx = ss ^ (r & 7);                      // inverse swizzle on source
            const u16* src = (half < 2)
                ? (A + (arow0 + half * 128 + r) * (long)FAN + k0 + sx * 8)
                : (W + (bcol0 + (half - 2) * 128 + r) * (long)FAN + k0 + sx * 8);
            gload16(src, &lds[buf][half][i * 4096 + wid * 512]);
        }
    };

    // prologue: K-tile 0 (all 4 halves) -> buf0; K-tile 1 B-halves -> buf1.
    stageHalf(0, 0, 0); stageHalf(0, 1, 0); stageHalf(0, 2, 0); stageHalf(0, 3, 0);
    stageHalf(1, 2, 1); stageHalf(1, 3, 1);
    asm volatile("s_waitcnt vmcnt(4)" ::: "memory");
    __builtin_amdgcn_s_barrier();

    const u16* Ah[2] = { &lds[0][wm][0],            &lds[1][wm][0] };
    const u16* Bh[2] = { &lds[0][2 + (wn >> 1)][0], &lds[1][2 + (wn >> 1)][0] };
    const int lrB0 = (wn & 1) * 64;

#pragma unroll 1
    for (int tile = 0; tile < TILES_PER_BLK; ++tile) {
        const int kb = tile * KTILES;
#pragma unroll 1
        for (int t = 0; t < NITER; ++t) {
            bfrag bq[4][2];
#pragma unroll
            for (int p = 0; p < 8; ++p) {
                const int q  = p & 3;
                const int lt = p >> 2;
                bfrag aq[2][2];
                if (q == 0) {                                 // B-frags once per K-tile
#pragma unroll
                    for (int nf = 0; nf < 4; ++nf)
#pragma unroll
                        for (int kk = 0; kk < 2; ++kk) {
                            const int lr = lrB0 + nf * 16 + (lane & 15);
                            const int sl = (kk * 4 + (lane >> 4)) ^ (lane & 7);
                            bq[nf][kk] = *(const bfrag*)(Bh[lt] + lr * 64 + sl * 8);
                        }
                }
#pragma unroll
                for (int m2 = 0; m2 < 2; ++m2)                // A quadrant (2 M-frags)
#pragma unroll
                    for (int kk = 0; kk < 2; ++kk) {
                        const int lr = (q * 2 + m2) * 16 + (lane & 15);
                        const int sl = (kk * 4 + (lane >> 4)) ^ (lane & 7);
                        aq[m2][kk] = *(const bfrag*)(Ah[lt] + lr * 64 + sl * 8);
                    }
                // continuous staging schedule (uniform; dummies clamp past the end)
                if (p == 0)      stageHalf(1, 0, kb + 2 * t + 1);
                else if (p == 1) stageHalf(1, 1, kb + 2 * t + 1);
                else if (p == 2) stageHalf(0, 2, kb + 2 * t + 2);
                else if (p == 3) stageHalf(0, 3, kb + 2 * t + 2);
                else if (p == 4) stageHalf(0, 0, kb + 2 * t + 2);
                else if (p == 5) stageHalf(0, 1, kb + 2 * t + 2);
                else if (p == 6) stageHalf(1, 2, kb + 2 * t + 3);
                else             stageHalf(1, 3, kb + 2 * t + 3);

                if (q == 0) asm volatile("s_waitcnt lgkmcnt(8)" ::: "memory");
                __builtin_amdgcn_s_barrier();
                asm volatile("s_waitcnt lgkmcnt(0)" ::: "memory");
                __builtin_amdgcn_s_setprio(1);
#pragma unroll
                for (int m2 = 0; m2 < 2; ++m2)
#pragma unroll
                    for (int nf = 0; nf < 4; ++nf)
#pragma unroll
                        for (int kk = 0; kk < 2; ++kk)
                            // NORMAL operand order (round-6 measured-best):
                            // D row=(lane>>4)*4+reg -> M, col=lane&15 -> N
                            acc[q * 2 + m2][nf] = __builtin_amdgcn_mfma_f32_16x16x32_bf16(
                                aq[m2][kk], bq[nf][kk], acc[q * 2 + m2][nf], 0, 0, 0);
                __builtin_amdgcn_s_setprio(0);
                if (q == 3) asm volatile("s_waitcnt vmcnt(4)" ::: "memory");  // counted, never 0
                __builtin_amdgcn_s_barrier();
            }
        }

        // epilogue (round-6 measured: WRITE clean 262 MB): per (mf,nf) 4 scalar u16
        // stores down the M rows; 16-lane groups cover 32B col segments. Bias fused.
        const long bcol0 = ((long)bn4 + tile) * BN;
        float bvs[4];
#pragma unroll
        for (int nf = 0; nf < 4; ++nf)
            bvs[nf] = biasAll[bcol0 + wn * 64 + nf * 16 + (lane & 15)];
#pragma unroll
        for (int mf = 0; mf < 8; ++mf)
#pragma unroll
            for (int nf = 0; nf < 4; ++nf) {
                const long row = arow0 + wm * 128 + mf * 16 + ((lane >> 4) << 2);
                const long col = bcol0 + wn * 64 + nf * 16 + (lane & 15);
                u16* p = Cg + row * (long)NCOL + col;
#pragma unroll
                for (int r = 0; r < 4; ++r)
                    p[(long)r * NCOL] = f2b(acc[mf][nf][r] + bvs[nf]);
                acc[mf][nf] = facc{0.f, 0.f, 0.f, 0.f};
            }
    }
}

// ---------------- kernel 2: grid-stride LN + activations, params register-resident ----
__global__ __launch_bounds__(256)
void lstm_act(const u16* __restrict__ pre, const float* __restrict__ pc,
              const float* __restrict__ gf, const float* __restrict__ btf,
              const float* __restrict__ gi, const float* __restrict__ bti,
              const float* __restrict__ go, const float* __restrict__ bto,
              const float* __restrict__ gj, const float* __restrict__ btj,
              const float* __restrict__ gc, const float* __restrict__ btc,
              float* __restrict__ out_h, float* __restrict__ out_c, long rows)
{
    const int  lane = threadIdx.x & 63;
    const int  c0   = lane * 8;
    const long wave = (long)blockIdx.x * 4 + (threadIdx.x >> 6);
    const long totW = (long)gridDim.x * 4;

    const float* gs[4]  = { gf, gi, go, gj };
    const float* bts[4] = { btf, bti, bto, btj };
    float gg[4][8], tt[4][8], gcv[8], tcv[8];
#pragma unroll
    for (int g = 0; g < 4; ++g) {
        *(float4*)&gg[g][0] = *(const float4*)(gs[g] + c0);
        *(float4*)&gg[g][4] = *(const float4*)(gs[g] + c0 + 4);
        *(float4*)&tt[g][0] = *(const float4*)(bts[g] + c0);
        *(float4*)&tt[g][4] = *(const float4*)(bts[g] + c0 + 4);
    }
    *(float4*)&gcv[0] = *(const float4*)(gc + c0);
    *(float4*)&gcv[4] = *(const float4*)(gc + c0 + 4);
    *(float4*)&tcv[0] = *(const float4*)(btc + c0);
    *(float4*)&tcv[4] = *(const float4*)(btc + c0 + 4);

#pragma unroll 1
    for (long row = wave; row < rows; row += totW) {
        float a4[4][8];
#pragma unroll
        for (int g = 0; g < 4; ++g) {
            us8 pv = *(const us8*)(pre + row * NCOL + g * HDIM + c0);
            float y[8];
            float s = 0.f, ssum = 0.f;
#pragma unroll
            for (int e = 0; e < 8; ++e) {
                y[e] = b2f(pv[e]);                 // bias already added in GEMM
                s += y[e]; ssum += y[e] * y[e];
            }
            float mean, rstd;
            wave_meanrstd(s, ssum, mean, rstd);
#pragma unroll
            for (int e = 0; e < 8; ++e) {
                float z = (y[e] - mean) * rstd * gg[g][e] + tt[g][e];
                a4[g][e] = (g == 3) ? fast_tanh(z) : fast_sigmoid(z);
            }
        }

        float4 p0 = *(const float4*)(pc + row * HDIM + c0);
        float4 p1 = *(const float4*)(pc + row * HDIM + c0 + 4);
        float pcv[8] = { p0.x, p0.y, p0.z, p0.w, p1.x, p1.y, p1.z, p1.w };
        float cr[8];
        float s = 0.f, ssum = 0.f;
#pragma unroll
        for (int e = 0; e < 8; ++e) {
            cr[e] = a4[0][e] * pcv[e] + fminf(1.f - a4[0][e], a4[1][e]) * a4[3][e];
            s += cr[e]; ssum += cr[e] * cr[e];
        }
        float mean, rstd;
        wave_meanrstd(s, ssum, mean, rstd);
        float hv[8], cv[8];
#pragma unroll
        for (int e = 0; e < 8; ++e) {
            float cc = (cr[e] - mean) * rstd * gcv[e] + tcv[e];
            cv[e] = cc;
            hv[e] = a4[2][e] * cc;
        }
        f4v h0 = { hv[0], hv[1], hv[2], hv[3] };
        f4v h1 = { hv[4], hv[5], hv[6], hv[7] };
        f4v c0v = { cv[0], cv[1], cv[2], cv[3] };
        f4v c1v = { cv[4], cv[5], cv[6], cv[7] };
        __builtin_nontemporal_store(h0,  (f4v*)(out_h + row * HDIM + c0));
        __builtin_nontemporal_store(h1,  (f4v*)(out_h + row * HDIM + c0 + 4));
        __builtin_nontemporal_store(c0v, (f4v*)(out_c + row * HDIM + c0));
        __builtin_nontemporal_store(c1v, (f4v*)(out_c + row * HDIM + c0 + 4));
    }
}

// ---------------- fallback (only if ws too small): fp32 naive, no workspace ----------------
static __device__ __forceinline__ void ln_pair(
    float y0, float y1,
    const float* __restrict__ gam, const float* __restrict__ bet, int c0,
    float* red, int lane, int wid, float& o0, float& o1)
{
    float s = y0 + y1, ss = y0 * y0 + y1 * y1;
#pragma unroll
    for (int o = 32; o; o >>= 1) { s += __shfl_down(s, o); ss += __shfl_down(ss, o); }
    if (lane == 0) { red[wid * 2] = s; red[wid * 2 + 1] = ss; }
    __syncthreads();
    float S  = red[0] + red[2] + red[4] + red[6];
    float SS = red[1] + red[3] + red[5] + red[7];
    __syncthreads();
    float mean = S * (1.f / 512.f);
    float var  = (SS - 512.f * mean * mean) * (1.f / 511.f);
    float rstd = 1.f / (sqrtf(fmaxf(var, 0.f)) + EPS);
    o0 = (y0 - mean) * rstd * gam[c0]     + bet[c0];
    o1 = (y1 - mean) * rstd * gam[c0 + 1] + bet[c0 + 1];
}

__global__ __launch_bounds__(256)
void lstm_naive(const float* __restrict__ x, const float* __restrict__ ph, const float* __restrict__ pc,
                const float* __restrict__ Wf, const float* __restrict__ bf_,
                const float* __restrict__ Wi, const float* __restrict__ bi_,
                const float* __restrict__ Wo, const float* __restrict__ bo_,
                const float* __restrict__ Wj, const float* __restrict__ bj_,
                const float* __restrict__ gf, const float* __restrict__ btf,
                const float* __restrict__ gi, const float* __restrict__ bti,
                const float* __restrict__ go, const float* __restrict__ bto,
                const float* __restrict__ gj, const float* __restrict__ btj,
                const float* __restrict__ gc, const float* __restrict__ btc,
                float* __restrict__ out_h, float* __restrict__ out_c)
{
    __shared__ float comb[FAN];
    __shared__ float red[8];
    const int b = blockIdx.x, t = threadIdx.x;
    const int lane = t & 63, wid = t >> 6;
    for (int k = t; k < D_IN; k += 256) {
        comb[k]        = x[(long)b * D_IN + k];
        comb[D_IN + k] = ph[(long)b * HDIM + k];
    }
    __syncthreads();
    const int c0 = t * 2;
    const float* Ws[4]  = { Wf, Wi, Wo, Wj };
    const float* bs[4]  = { bf_, bi_, bo_, bj_ };
    const float* gs[4]  = { gf, gi, go, gj };
    const float* bts[4] = { btf, bti, bto, btj };
    float a[4][2];
#pragma unroll
    for (int g = 0; g < 4; ++g) {
        float y[2];
#pragma unroll
        for (int e = 0; e < 2; ++e) {
            const float4* w4 = (const float4*)(Ws[g] + (long)(c0 + e) * FAN);
            const float4* c4 = (const float4*)comb;
            float s = 0.f;
            for (int k = 0; k < FAN / 4; ++k) {
                float4 wv = w4[k], cv = c4[k];
                s += wv.x * cv.x + wv.y * cv.y + wv.z * cv.z + wv.w * cv.w;
            }
            y[e] = s + bs[g][c0 + e];
        }
        ln_pair(y[0], y[1], gs[g], bts[g], c0, red, lane, wid, a[g][0], a[g][1]);
        if (g == 3) { a[g][0] = tanhf(a[g][0]); a[g][1] = tanhf(a[g][1]); }
        else        { a[g][0] = 1.f / (1.f + expf(-a[g][0]));
                      a[g][1] = 1.f / (1.f + expf(-a[g][1])); }
    }
    float2 pcv = *(const float2*)(pc + (long)b * HDIM + c0);
    float f0 = a[0][0], i0 = a[1][0], o0 = a[2][0], j0 = a[3][0];
    float f1 = a[0][1], i1 = a[1][1], o1 = a[2][1], j1 = a[3][1];
    float cr0 = f0 * pcv.x + fminf(1.f - f0, i0) * j0;
    float cr1 = f1 * pcv.y + fminf(1.f - f1, i1) * j1;
    float cc0, cc1;
    ln_pair(cr0, cr1, gc, btc, c0, red, lane, wid, cc0, cc1);
    *(float2*)(out_h + (long)b * HDIM + c0) = make_float2(o0 * cc0, o1 * cc1);
    *(float2*)(out_c + (long)b * HDIM + c0) = make_float2(cc0, cc1);
}

// ---------------- launcher ----------------
extern "C" void kernel_launch(void* const* d_in, const int* in_sizes, int n_in,
                              void* d_out, int out_size, void* d_ws, size_t ws_size,
                              hipStream_t stream)
{
    const float* x   = (const float*)d_in[0];
    const float* ph  = (const float*)d_in[1];
    const float* pc  = (const float*)d_in[2];
    const float* Wf  = (const float*)d_in[3];
    const float* bf_ = (const float*)d_in[4];
    const float* Wi  = (const float*)d_in[5];
    const float* bi_ = (const float*)d_in[6];
    const float* Wo  = (const float*)d_in[7];
    const float* bo_ = (const float*)d_in[8];
    const float* Wj  = (const float*)d_in[9];
    const float* bj_ = (const float*)d_in[10];
    const float* gf  = (const float*)d_in[11];
    const float* btf = (const float*)d_in[12];
    const float* gi  = (const float*)d_in[13];
    const float* bti = (const float*)d_in[14];
    const float* go  = (const float*)d_in[15];
    const float* bto = (const float*)d_in[16];
    const float* gj  = (const float*)d_in[17];
    const float* btj = (const float*)d_in[18];
    const float* gc  = (const float*)d_in[19];
    const float* btc = (const float*)d_in[20];
    float* out_h = (float*)d_out;
    float* out_c = out_h + (size_t)B_ROWS * HDIM;

    const size_t combElems  = (size_t)B_ROWS * FAN;            // bf16
    const size_t wElems     = (size_t)NCOL * FAN;              // bf16
    const size_t biasBytes  = (size_t)NCOL * sizeof(float);    // 8 KB
    const size_t fixedBytes = (combElems + wElems) * 2 + biasBytes;

    long slabRows = 0;
    if (ws_size > fixedBytes) {
        size_t avail = ws_size - fixedBytes;
        slabRows = (long)(avail / ((size_t)NCOL * 2));
        slabRows &= ~1023L;                                 // grid = (rows/256)*2 must be %8
        if (slabRows > SLAB_ROWS) slabRows = SLAB_ROWS;     // 2 slabs: L3-hot act reads
    }

    if (slabRows >= 1024) {
        u16*   comb    = (u16*)d_ws;
        u16*   Wall    = comb + combElems;
        float* biasAll = (float*)(Wall + wElems);
        u16*   pre     = (u16*)(biasAll + NCOL);
        pack_combined<<<dim3((unsigned)((B_ROWS * (long)D_IN / 4 + 255) / 256)), dim3(256), 0, stream>>>(x, ph, comb);
        pack_w<<<dim3((unsigned)(((long)NCOL * FAN / 4 + 255) / 256)), dim3(256), 0, stream>>>(Wf, Wi, Wo, Wj, Wall);
        pack_bias<<<dim3(8), dim3(256), 0, stream>>>(bf_, bi_, bo_, bj_, biasAll);
        for (long r0 = 0; r0 < B_ROWS; r0 += slabRows) {
            long rows = B_ROWS - r0; if (rows > slabRows) rows = slabRows;
            const unsigned nwg = (unsigned)((rows / BM) * 2);   // 2 blocks per M-tile (4 N-tiles each)
            gemm_gates<<<dim3(nwg), dim3(512), 0, stream>>>(comb + r0 * FAN, Wall, biasAll, pre);
            lstm_act<<<dim3(2048), dim3(256), 0, stream>>>(
                pre, pc + r0 * HDIM,
                gf, btf, gi, bti, go, bto, gj, btj, gc, btc,
                out_h + r0 * HDIM, out_c + r0 * HDIM, rows);
        }
    } else {
        lstm_naive<<<dim3(B_ROWS), dim3(256), 0, stream>>>(
            x, ph, pc, Wf, bf_, Wi, bi_, Wo, bo_, Wj, bj_,
            gf, btf, gi, bti, go, bto, gj, btj, gc, btc, out_h, out_c);
    }
}

// Round 14
// 495.393 us; speedup vs baseline: 1.1371x; 1.0035x over previous
//
#include <hip/hip_runtime.h>
#include <math.h>

// ---------------- problem constants ----------------
#define B_ROWS 65536
#define D_IN   512
#define HDIM   512
#define FAN    1024          // D_IN + H
#define NCOL   2048          // 4 gates * HDIM
#define EPS    1e-5f

// GEMM tile (256^2 8-phase, persistent-lite: 4 N-tiles per block), 16x16x32 MFMA
#define BM 256
#define BN 256
#define BK 64
#define KTILES (FAN / BK)    // 16 per output tile
#define NITER  (KTILES / 2)  // 8 iterations, 2 K-tiles each
#define TILES_PER_BLK 4      // N-tiles per block (half of NCOL/BN)
#define SLAB_ROWS 32768L     // 2 slabs: pre-slab (128 MB) stays L3-resident for act

typedef unsigned short u16;
using bfrag = __attribute__((ext_vector_type(8))) short;          // 8 bf16 (4 VGPRs)
using facc  = __attribute__((ext_vector_type(4))) float;          // 4 fp32 acc
using us4   = __attribute__((ext_vector_type(4))) unsigned short;
using us8   = __attribute__((ext_vector_type(8))) unsigned short;
using f4v   = __attribute__((ext_vector_type(4))) float;          // clang vec for nontemporal

// ---------------- helpers ----------------
static __device__ __forceinline__ u16 f2b(float f) {              // fp32 -> bf16 RNE
    unsigned u = __builtin_bit_cast(unsigned, f);
    u += 0x7fffu + ((u >> 16) & 1u);
    return (u16)(u >> 16);
}
static __device__ __forceinline__ float b2f(u16 h) {
    unsigned u = ((unsigned)h) << 16;
    return __builtin_bit_cast(float, u);
}
static __device__ __forceinline__ void gload16(const u16* g, u16* l) {
    __builtin_amdgcn_global_load_lds(
        (const __attribute__((address_space(1))) void*)g,
        (__attribute__((address_space(3))) void*)l, 16, 0, 0);
}
static __device__ __forceinline__ void wave_meanrstd(float s, float ss, float& mean, float& rstd)
{
#pragma unroll
    for (int o = 1; o < 64; o <<= 1) { s += __shfl_xor(s, o); ss += __shfl_xor(ss, o); }
    mean = s * (1.f / 512.f);
    float var = (ss - 512.f * mean * mean) * (1.f / 511.f);
    rstd = 1.f / (sqrtf(fmaxf(var, 0.f)) + EPS);
}
static __device__ __forceinline__ float fast_sigmoid(float z) {
    return __fdividef(1.f, 1.f + __expf(-z));
}
static __device__ __forceinline__ float fast_tanh(float z) {
    return __fdividef(2.f, 1.f + __expf(-2.f * z)) - 1.f;
}

// ---------------- kernel 0: fused pack (combined bf16 + W bf16), one launch ----------
#define COMB_JOBS ((long)B_ROWS * D_IN / 4)     // 8388608 float4-pairs
#define W_JOBS    ((long)NCOL * FAN / 4)        //  524288 float4s
__global__ void pack_all(const float* __restrict__ x, const float* __restrict__ ph,
                         const float* __restrict__ Wf, const float* __restrict__ Wi,
                         const float* __restrict__ Wo, const float* __restrict__ Wj,
                         u16* __restrict__ comb, u16* __restrict__ Wall)
{
    long i = (long)blockIdx.x * 256 + threadIdx.x;
    if (i < COMB_JOBS) {
        long e = i * 4;
        long b = e >> 9;
        int  d = (int)(e & 511);
        float4 xv = *(const float4*)(x + e);
        float4 hv = *(const float4*)(ph + e);
        us4 xb = { f2b(xv.x), f2b(xv.y), f2b(xv.z), f2b(xv.w) };
        us4 hb = { f2b(hv.x), f2b(hv.y), f2b(hv.z), f2b(hv.w) };
        *(us4*)(comb + b * FAN + d)        = xb;
        *(us4*)(comb + b * FAN + D_IN + d) = hb;
    } else if (i < COMB_JOBS + W_JOBS) {
        long e = (i - COMB_JOBS) * 4;
        int  g = (int)(e >> 19);                               // 512*1024 elems per gate
        long rem = e & 524287L;
        const float* src = (g == 0) ? Wf : (g == 1) ? Wi : (g == 2) ? Wo : Wj;
        float4 v = *(const float4*)(src + rem);
        us4 p = { f2b(v.x), f2b(v.y), f2b(v.z), f2b(v.w) };
        *(us4*)(Wall + e) = p;
    }
}

// ---------------- kernel 1: persistent-lite 256^2 8-phase GEMM (round-6 core) ----------
// Round-13 measured-best core unchanged: normal operand order mfma(A,B), continuous
// staging across 4 N-tiles, counted vmcnt(4), scalar-u16 epilogue (WRITE clean 262 MB).
// Delta vs round 13: bias read directly from the 4 original arrays (wave-uniform gate
// select -- the 64-col wave slice never crosses a 512-col gate boundary), no biasAll.
__global__ __launch_bounds__(512)
void gemm_gates(const u16* __restrict__ A, const u16* __restrict__ W,
                const float* __restrict__ bf_, const float* __restrict__ bi_,
                const float* __restrict__ bo_, const float* __restrict__ bj_,
                u16* __restrict__ Cg)
{
    __shared__ u16 lds[2][4][8192];

    const int tid  = threadIdx.x;
    const int lane = tid & 63;
    const int wid  = tid >> 6;
    const int wm   = wid >> 2;         // 0..1
    const int wn   = wid & 3;          // 0..3

    // XCD-aware bijective swizzle (nwg = mtiles*2, always a multiple of 8).
    const int nwg = gridDim.x;
    const int swz = (blockIdx.x & 7) * (nwg >> 3) + (blockIdx.x >> 3);
    const long bm  = swz >> 1;
    const int  bn4 = (swz & 1) * TILES_PER_BLK;     // first N-tile: 0 or 4
    const long arow0 = bm * BM;

    const int sr = tid >> 3;           // staging row within half (i adds 64)
    const int ss = tid & 7;            // linear 16B slot

    facc acc[8][4];
#pragma unroll
    for (int i = 0; i < 8; ++i)
#pragma unroll
        for (int j = 0; j < 4; ++j) acc[i][j] = facc{0.f, 0.f, 0.f, 0.f};

    auto stageHalf = [&](int buf, int half, int ktg) {
        if (ktg >= TILES_PER_BLK * KTILES) ktg = 0;           // dummy: valid addr, never read
        const long k0    = (long)(ktg & (KTILES - 1)) * BK;
        const long bcol0 = ((long)bn4 + (ktg >> 4)) * BN;     // N-tile for this K-chunk
#pragma unroll
        for (int i = 0; i < 2; ++i) {
            const int r  = sr + i * 64;
            const int sx = ss ^ (r & 7);                      // inverse swizzle on source
            const u16* src = (half < 2)
                ? (A + (arow0 + half * 128 + r) * (long)FAN + k0 + sx * 8)
                : (W + (bcol0 + (half - 2) * 128 + r) * (long)FAN + k0 + sx * 8);
            gload16(src, &lds[buf][half][i * 4096 + wid * 512]);
        }
    };

    // prologue: K-tile 0 (all 4 halves) -> buf0; K-tile 1 B-halves -> buf1.
    stageHalf(0, 0, 0); stageHalf(0, 1, 0); stageHalf(0, 2, 0); stageHalf(0, 3, 0);
    stageHalf(1, 2, 1); stageHalf(1, 3, 1);
    asm volatile("s_waitcnt vmcnt(4)" ::: "memory");
    __builtin_amdgcn_s_barrier();

    const u16* Ah[2] = { &lds[0][wm][0],            &lds[1][wm][0] };
    const u16* Bh[2] = { &lds[0][2 + (wn >> 1)][0], &lds[1][2 + (wn >> 1)][0] };
    const int lrB0 = (wn & 1) * 64;

#pragma unroll 1
    for (int tile = 0; tile < TILES_PER_BLK; ++tile) {
        const int kb = tile * KTILES;
#pragma unroll 1
        for (int t = 0; t < NITER; ++t) {
            bfrag bq[4][2];
#pragma unroll
            for (int p = 0; p < 8; ++p) {
                const int q  = p & 3;
                const int lt = p >> 2;
                bfrag aq[2][2];
                if (q == 0) {                                 // B-frags once per K-tile
#pragma unroll
                    for (int nf = 0; nf < 4; ++nf)
#pragma unroll
                        for (int kk = 0; kk < 2; ++kk) {
                            const int lr = lrB0 + nf * 16 + (lane & 15);
                            const int sl = (kk * 4 + (lane >> 4)) ^ (lane & 7);
                            bq[nf][kk] = *(const bfrag*)(Bh[lt] + lr * 64 + sl * 8);
                        }
                }
#pragma unroll
                for (int m2 = 0; m2 < 2; ++m2)                // A quadrant (2 M-frags)
#pragma unroll
                    for (int kk = 0; kk < 2; ++kk) {
                        const int lr = (q * 2 + m2) * 16 + (lane & 15);
                        const int sl = (kk * 4 + (lane >> 4)) ^ (lane & 7);
                        aq[m2][kk] = *(const bfrag*)(Ah[lt] + lr * 64 + sl * 8);
                    }
                // continuous staging schedule (uniform; dummies clamp past the end)
                if (p == 0)      stageHalf(1, 0, kb + 2 * t + 1);
                else if (p == 1) stageHalf(1, 1, kb + 2 * t + 1);
                else if (p == 2) stageHalf(0, 2, kb + 2 * t + 2);
                else if (p == 3) stageHalf(0, 3, kb + 2 * t + 2);
                else if (p == 4) stageHalf(0, 0, kb + 2 * t + 2);
                else if (p == 5) stageHalf(0, 1, kb + 2 * t + 2);
                else if (p == 6) stageHalf(1, 2, kb + 2 * t + 3);
                else             stageHalf(1, 3, kb + 2 * t + 3);

                if (q == 0) asm volatile("s_waitcnt lgkmcnt(8)" ::: "memory");
                __builtin_amdgcn_s_barrier();
                asm volatile("s_waitcnt lgkmcnt(0)" ::: "memory");
                __builtin_amdgcn_s_setprio(1);
#pragma unroll
                for (int m2 = 0; m2 < 2; ++m2)
#pragma unroll
                    for (int nf = 0; nf < 4; ++nf)
#pragma unroll
                        for (int kk = 0; kk < 2; ++kk)
                            // NORMAL operand order (round-6 measured-best):
                            // D row=(lane>>4)*4+reg -> M, col=lane&15 -> N
                            acc[q * 2 + m2][nf] = __builtin_amdgcn_mfma_f32_16x16x32_bf16(
                                aq[m2][kk], bq[nf][kk], acc[q * 2 + m2][nf], 0, 0, 0);
                __builtin_amdgcn_s_setprio(0);
                if (q == 3) asm volatile("s_waitcnt vmcnt(4)" ::: "memory");  // counted, never 0
                __builtin_amdgcn_s_barrier();
            }
        }

        // epilogue (round-6 measured: WRITE clean 262 MB): per (mf,nf) 4 scalar u16
        // stores down the M rows. Bias: wave-uniform gate select, no packed buffer.
        const long bcol0 = ((long)bn4 + tile) * BN;
        const int  wcol0 = (int)(bcol0 & 2047) + wn * 64;     // wave slice start col
        const int  gate  = wcol0 >> 9;                        // constant per wave/tile
        const float* bsrc = (gate == 0) ? bf_ : (gate == 1) ? bi_
                          : (gate == 2) ? bo_ : bj_;
        const int  gidx0 = wcol0 & 511;                       // within-gate col base
        float bvs[4];
#pragma unroll
        for (int nf = 0; nf < 4; ++nf)
            bvs[nf] = bsrc[gidx0 + nf * 16 + (lane & 15)];
#pragma unroll
        for (int mf = 0; mf < 8; ++mf)
#pragma unroll
            for (int nf = 0; nf < 4; ++nf) {
                const long row = arow0 + wm * 128 + mf * 16 + ((lane >> 4) << 2);
                const long col = bcol0 + wn * 64 + nf * 16 + (lane & 15);
                u16* p = Cg + row * (long)NCOL + col;
#pragma unroll
                for (int r = 0; r < 4; ++r)
                    p[(long)r * NCOL] = f2b(acc[mf][nf][r] + bvs[nf]);
                acc[mf][nf] = facc{0.f, 0.f, 0.f, 0.f};
            }
    }
}

// ---------------- kernel 2: grid-stride LN + activations, params register-resident ----
__global__ __launch_bounds__(256)
void lstm_act(const u16* __restrict__ pre, const float* __restrict__ pc,
              const float* __restrict__ gf, const float* __restrict__ btf,
              const float* __restrict__ gi, const float* __restrict__ bti,
              const float* __restrict__ go, const float* __restrict__ bto,
              const float* __restrict__ gj, const float* __restrict__ btj,
              const float* __restrict__ gc, const float* __restrict__ btc,
              float* __restrict__ out_h, float* __restrict__ out_c, long rows)
{
    const int  lane = threadIdx.x & 63;
    const int  c0   = lane * 8;
    const long wave = (long)blockIdx.x * 4 + (threadIdx.x >> 6);
    const long totW = (long)gridDim.x * 4;

    const float* gs[4]  = { gf, gi, go, gj };
    const float* bts[4] = { btf, bti, bto, btj };
    float gg[4][8], tt[4][8], gcv[8], tcv[8];
#pragma unroll
    for (int g = 0; g < 4; ++g) {
        *(float4*)&gg[g][0] = *(const float4*)(gs[g] + c0);
        *(float4*)&gg[g][4] = *(const float4*)(gs[g] + c0 + 4);
        *(float4*)&tt[g][0] = *(const float4*)(bts[g] + c0);
        *(float4*)&tt[g][4] = *(const float4*)(bts[g] + c0 + 4);
    }
    *(float4*)&gcv[0] = *(const float4*)(gc + c0);
    *(float4*)&gcv[4] = *(const float4*)(gc + c0 + 4);
    *(float4*)&tcv[0] = *(const float4*)(btc + c0);
    *(float4*)&tcv[4] = *(const float4*)(btc + c0 + 4);

#pragma unroll 1
    for (long row = wave; row < rows; row += totW) {
        float a4[4][8];
#pragma unroll
        for (int g = 0; g < 4; ++g) {
            us8 pv = *(const us8*)(pre + row * NCOL + g * HDIM + c0);
            float y[8];
            float s = 0.f, ssum = 0.f;
#pragma unroll
            for (int e = 0; e < 8; ++e) {
                y[e] = b2f(pv[e]);                 // bias already added in GEMM
                s += y[e]; ssum += y[e] * y[e];
            }
            float mean, rstd;
            wave_meanrstd(s, ssum, mean, rstd);
#pragma unroll
            for (int e = 0; e < 8; ++e) {
                float z = (y[e] - mean) * rstd * gg[g][e] + tt[g][e];
                a4[g][e] = (g == 3) ? fast_tanh(z) : fast_sigmoid(z);
            }
        }

        float4 p0 = *(const float4*)(pc + row * HDIM + c0);
        float4 p1 = *(const float4*)(pc + row * HDIM + c0 + 4);
        float pcv[8] = { p0.x, p0.y, p0.z, p0.w, p1.x, p1.y, p1.z, p1.w };
        float cr[8];
        float s = 0.f, ssum = 0.f;
#pragma unroll
        for (int e = 0; e < 8; ++e) {
            cr[e] = a4[0][e] * pcv[e] + fminf(1.f - a4[0][e], a4[1][e]) * a4[3][e];
            s += cr[e]; ssum += cr[e] * cr[e];
        }
        float mean, rstd;
        wave_meanrstd(s, ssum, mean, rstd);
        float hv[8], cv[8];
#pragma unroll
        for (int e = 0; e < 8; ++e) {
            float cc = (cr[e] - mean) * rstd * gcv[e] + tcv[e];
            cv[e] = cc;
            hv[e] = a4[2][e] * cc;
        }
        f4v h0 = { hv[0], hv[1], hv[2], hv[3] };
        f4v h1 = { hv[4], hv[5], hv[6], hv[7] };
        f4v c0v = { cv[0], cv[1], cv[2], cv[3] };
        f4v c1v = { cv[4], cv[5], cv[6], cv[7] };
        __builtin_nontemporal_store(h0,  (f4v*)(out_h + row * HDIM + c0));
        __builtin_nontemporal_store(h1,  (f4v*)(out_h + row * HDIM + c0 + 4));
        __builtin_nontemporal_store(c0v, (f4v*)(out_c + row * HDIM + c0));
        __builtin_nontemporal_store(c1v, (f4v*)(out_c + row * HDIM + c0 + 4));
    }
}

// ---------------- fallback (only if ws too small): fp32 naive, no workspace ----------------
static __device__ __forceinline__ void ln_pair(
    float y0, float y1,
    const float* __restrict__ gam, const float* __restrict__ bet, int c0,
    float* red, int lane, int wid, float& o0, float& o1)
{
    float s = y0 + y1, ss = y0 * y0 + y1 * y1;
#pragma unroll
    for (int o = 32; o; o >>= 1) { s += __shfl_down(s, o); ss += __shfl_down(ss, o); }
    if (lane == 0) { red[wid * 2] = s; red[wid * 2 + 1] = ss; }
    __syncthreads();
    float S  = red[0] + red[2] + red[4] + red[6];
    float SS = red[1] + red[3] + red[5] + red[7];
    __syncthreads();
    float mean = S * (1.f / 512.f);
    float var  = (SS - 512.f * mean * mean) * (1.f / 511.f);
    float rstd = 1.f / (sqrtf(fmaxf(var, 0.f)) + EPS);
    o0 = (y0 - mean) * rstd * gam[c0]     + bet[c0];
    o1 = (y1 - mean) * rstd * gam[c0 + 1] + bet[c0 + 1];
}

__global__ __launch_bounds__(256)
void lstm_naive(const float* __restrict__ x, const float* __restrict__ ph, const float* __restrict__ pc,
                const float* __restrict__ Wf, const float* __restrict__ bf_,
                const float* __restrict__ Wi, const float* __restrict__ bi_,
                const float* __restrict__ Wo, const float* __restrict__ bo_,
                const float* __restrict__ Wj, const float* __restrict__ bj_,
                const float* __restrict__ gf, const float* __restrict__ btf,
                const float* __restrict__ gi, const float* __restrict__ bti,
                const float* __restrict__ go, const float* __restrict__ bto,
                const float* __restrict__ gj, const float* __restrict__ btj,
                const float* __restrict__ gc, const float* __restrict__ btc,
                float* __restrict__ out_h, float* __restrict__ out_c)
{
    __shared__ float comb[FAN];
    __shared__ float red[8];
    const int b = blockIdx.x, t = threadIdx.x;
    const int lane = t & 63, wid = t >> 6;
    for (int k = t; k < D_IN; k += 256) {
        comb[k]        = x[(long)b * D_IN + k];
        comb[D_IN + k] = ph[(long)b * HDIM + k];
    }
    __syncthreads();
    const int c0 = t * 2;
    const float* Ws[4]  = { Wf, Wi, Wo, Wj };
    const float* bs[4]  = { bf_, bi_, bo_, bj_ };
    const float* gs[4]  = { gf, gi, go, gj };
    const float* bts[4] = { btf, bti, bto, btj };
    float a[4][2];
#pragma unroll
    for (int g = 0; g < 4; ++g) {
        float y[2];
#pragma unroll
        for (int e = 0; e < 2; ++e) {
            const float4* w4 = (const float4*)(Ws[g] + (long)(c0 + e) * FAN);
            const float4* c4 = (const float4*)comb;
            float s = 0.f;
            for (int k = 0; k < FAN / 4; ++k) {
                float4 wv = w4[k], cv = c4[k];
                s += wv.x * cv.x + wv.y * cv.y + wv.z * cv.z + wv.w * cv.w;
            }
            y[e] = s + bs[g][c0 + e];
        }
        ln_pair(y[0], y[1], gs[g], bts[g], c0, red, lane, wid, a[g][0], a[g][1]);
        if (g == 3) { a[g][0] = tanhf(a[g][0]); a[g][1] = tanhf(a[g][1]); }
        else        { a[g][0] = 1.f / (1.f + expf(-a[g][0]));
                      a[g][1] = 1.f / (1.f + expf(-a[g][1])); }
    }
    float2 pcv = *(const float2*)(pc + (long)b * HDIM + c0);
    float f0 = a[0][0], i0 = a[1][0], o0 = a[2][0], j0 = a[3][0];
    float f1 = a[0][1], i1 = a[1][1], o1 = a[2][1], j1 = a[3][1];
    float cr0 = f0 * pcv.x + fminf(1.f - f0, i0) * j0;
    float cr1 = f1 * pcv.y + fminf(1.f - f1, i1) * j1;
    float cc0, cc1;
    ln_pair(cr0, cr1, gc, btc, c0, red, lane, wid, cc0, cc1);
    *(float2*)(out_h + (long)b * HDIM + c0) = make_float2(o0 * cc0, o1 * cc1);
    *(float2*)(out_c + (long)b * HDIM + c0) = make_float2(cc0, cc1);
}

// ---------------- launcher ----------------
extern "C" void kernel_launch(void* const* d_in, const int* in_sizes, int n_in,
                              void* d_out, int out_size, void* d_ws, size_t ws_size,
                              hipStream_t stream)
{
    const float* x   = (const float*)d_in[0];
    const float* ph  = (const float*)d_in[1];
    const float* pc  = (const float*)d_in[2];
    const float* Wf  = (const float*)d_in[3];
    const float* bf_ = (const float*)d_in[4];
    const float* Wi  = (const float*)d_in[5];
    const float* bi_ = (const float*)d_in[6];
    const float* Wo  = (const float*)d_in[7];
    const float* bo_ = (const float*)d_in[8];
    const float* Wj  = (const float*)d_in[9];
    const float* bj_ = (const float*)d_in[10];
    const float* gf  = (const float*)d_in[11];
    const float* btf = (const float*)d_in[12];
    const float* gi  = (const float*)d_in[13];
    const float* bti = (const float*)d_in[14];
    const float* go  = (const float*)d_in[15];
    const float* bto = (const float*)d_in[16];
    const float* gj  = (const float*)d_in[17];
    const float* btj = (const float*)d_in[18];
    const float* gc  = (const float*)d_in[19];
    const float* btc = (const float*)d_in[20];
    float* out_h = (float*)d_out;
    float* out_c = out_h + (size_t)B_ROWS * HDIM;

    const size_t combElems  = (size_t)B_ROWS * FAN;            // bf16
    const size_t wElems     = (size_t)NCOL * FAN;              // bf16
    const size_t fixedBytes = (combElems + wElems) * 2;

    long slabRows = 0;
    if (ws_size > fixedBytes) {
        size_t avail = ws_size - fixedBytes;
        slabRows = (long)(avail / ((size_t)NCOL * 2));
        slabRows &= ~1023L;                                 // grid = (rows/256)*2 must be %8
        if (slabRows > SLAB_ROWS) slabRows = SLAB_ROWS;     // 2 slabs: L3-hot act reads
    }

    if (slabRows >= 1024) {
        u16* comb = (u16*)d_ws;
        u16* Wall = comb + combElems;
        u16* pre  = Wall + wElems;
        const long packBlocks = (COMB_JOBS + W_JOBS + 255) / 256;
        pack_all<<<dim3((unsigned)packBlocks), dim3(256), 0, stream>>>(
            x, ph, Wf, Wi, Wo, Wj, comb, Wall);
        for (long r0 = 0; r0 < B_ROWS; r0 += slabRows) {
            long rows = B_ROWS - r0; if (rows > slabRows) rows = slabRows;
            const unsigned nwg = (unsigned)((rows / BM) * 2);   // 2 blocks per M-tile (4 N-tiles each)
            gemm_gates<<<dim3(nwg), dim3(512), 0, stream>>>(
                comb + r0 * FAN, Wall, bf_, bi_, bo_, bj_, pre);
            lstm_act<<<dim3(2048), dim3(256), 0, stream>>>(
                pre, pc + r0 * HDIM,
                gf, btf, gi, bti, go, bto, gj, btj, gc, btc,
                out_h + r0 * HDIM, out_c + r0 * HDIM, rows);
        }
    } else {
        lstm_naive<<<dim3(B_ROWS), dim3(256), 0, stream>>>(
            x, ph, pc, Wf, bf_, Wi, bi_, Wo, bo_, Wj, bj_,
            gf, btf, gi, bti, go, bto, gj, btj, gc, btc, out_h, out_c);
    }
}